// Round 16
// baseline (428.271 us; speedup 1.0000x reference)
//
#include <hip/hip_runtime.h>
#include <hip/hip_bf16.h>
#include <hip/hip_fp16.h>
#include <stdint.h>
#include <math.h>

#define N_IMG 4
#define CIN 256
#define HFD 128
#define WFD 128
#define HW (HFD*WFD)        // 16384
#define NA 3
#define NPROP (NA*HW)       // 49152
#define PRE_NMS 2000
#define POST_NMS 300

__device__ __forceinline__ unsigned long long rl64(unsigned long long v, int i) {
    unsigned int lo = (unsigned int)__builtin_amdgcn_readlane((int)(unsigned int)v, i);
    unsigned int hi = (unsigned int)__builtin_amdgcn_readlane((int)(unsigned int)(v >> 32), i);
    return ((unsigned long long)hi << 32) | (unsigned long long)lo;
}

// PART layout: [chunk][c][p], chunk stride 1<<20 doubles, c stride 65536, p = (n<<14)+pos
__device__ __forceinline__ double sum8(const double* __restrict__ PART, size_t cp) {
    const size_t S = (size_t)1 << 20;
    double a = PART[cp] + PART[cp + S];
    double b = PART[cp + 2 * S] + PART[cp + 3 * S];
    double c = PART[cp + 4 * S] + PART[cp + 5 * S];
    double d = PART[cp + 6 * S] + PART[cp + 7 * S];
    return (a + b) + (c + d);
}

__device__ __forceinline__ void decode_box(int i, double dx, double dy, double dwv, double dhv,
                                           double& c1o, double& c2o, double& c3o, double& c4o) {
    int loc = i / 3, aa = i % 3;
    int hh = loc >> 7, wwi = loc & 127;
    double sx = (double)(wwi * 8), sy = (double)(hh * 8);
    double bx1 = (aa == 0) ? -91.0 : (aa == 1 ? -64.0 : -45.0);
    double by1 = (aa == 0) ? -45.0 : (aa == 1 ? -64.0 : -91.0);
    double x1 = sx + bx1, y1 = sy + by1, x2 = sx - bx1, y2 = sy - by1;
    double aw = x2 - x1, ahh = y2 - y1;
    double acx = y1 + aw * 0.5;   // (sic) swap, faithful to reference
    double acy = x1 + ahh * 0.5;  // (sic)
    double px = acx + dx * aw, py = acy + dy * ahh;
    double pw = aw * exp(dwv), ph = ahh * exp(dhv);
    double c1 = px - pw * 0.5, c2 = py - ph * 0.5, c3 = px + pw * 0.5, c4 = py + ph * 0.5;
    c1o = fmin(fmax(c1, 0.0), 1024.0);
    c2o = fmin(fmax(c2, 0.0), 1024.0);
    c3o = fmin(fmax(c3, 0.0), 1024.0);
    c4o = fmin(fmax(c4, 0.0), 1024.0);
}

// ---------------- K0: effective fp64 weights + selection-state init ----------------
__global__ __launch_bounds__(256) void k_effw64(const float* __restrict__ cw, const float* __restrict__ cb,
                                                const float* __restrict__ dw_, const float* __restrict__ db_,
                                                const float* __restrict__ rw_, const float* __restrict__ rb_,
                                                double* __restrict__ E64, double* __restrict__ EB64,
                                                unsigned long long* __restrict__ PSPREF,
                                                int* __restrict__ PSNEED,
                                                uint32_t* __restrict__ HIST,
                                                uint32_t* __restrict__ CNT)
{
    int b = blockIdx.x;
    int tid = threadIdx.x;
    if (b < 144) {
        __shared__ float hwl[15][260];
        __shared__ float wt[256][16];
        int k0 = b * 16;
        for (int idx = tid; idx < 15 * 256; idx += 256) {
            int c = idx >> 8, co = idx & 255;
            hwl[c][co] = (c < 3) ? dw_[c * 256 + co] : rw_[(c - 3) * 256 + co];
        }
        for (int idx = tid; idx < 4096; idx += 256) {
            int co = idx >> 4, kk = idx & 15;
            wt[co][kk] = cw[co * 2304 + k0 + kk];
        }
        __syncthreads();
        int kk = tid >> 4, c = tid & 15;
        double s = 0.0;
        if (c < 15) {
#pragma unroll 4
            for (int co = 0; co < 256; co++) s += (double)hwl[c][co] * (double)wt[co][kk];
        }
        E64[(k0 + kk) * 16 + c] = s;
    } else {
        if (tid < 16) {
            int c = tid;
            double s = 0.0; double hb = 0.0;
            if (c < 15) {
                const float* hw = (c < 3) ? (dw_ + c * 256) : (rw_ + (c - 3) * 256);
                for (int co = 0; co < 256; co++) s += (double)hw[co] * (double)cb[co];
                hb = (double)((c < 3) ? db_[c] : rb_[c - 3]);
            }
            EB64[c] = s + hb;
        }
        for (int i = tid; i < N_IMG * 2048; i += 256) HIST[i] = 0u;
        if (tid < N_IMG) { PSPREF[tid] = 0ull; PSNEED[tid] = PRE_NMS; CNT[tid] = 0u; }
    }
}

// ---------------- K1: dense fused 15-output 3x3 conv, fp64 acc, 8-way ci-split, 2-row tiles ----------------
// grid 2048 = 4 img x 64 row-pairs x 8 chunks(32 ci)
// block 256: q=tid&63 (row=q>>5, qq=q&31, w0=qq*4 -> 4 px), g=tid>>6 (4 ch each)
// Weights: wave-uniform s_load from global E64 (readfirstlane-forced), no LDS staging.
__global__ __launch_bounds__(256, 8) void k_conv64(const float* __restrict__ feat,
                                                   const double* __restrict__ E64,
                                                   double* __restrict__ PART)
{
    __shared__ float in_t[8][4][136];   // [ci][row h0-1..h0+2][4 + col]
    int b = blockIdx.x;
    int chunk = b & 7; int hp = (b >> 3) & 63; int n = b >> 9;
    int h0 = hp * 2;
    int tid = threadIdx.x;
    int q = tid & 63;
    int row = q >> 5, qq = q & 31, w0 = qq * 4;
    int g = tid >> 6;
    double acc[4][4];
#pragma unroll
    for (int cc = 0; cc < 4; cc++)
#pragma unroll
        for (int px = 0; px < 4; px++) acc[cc][px] = 0.0;

    for (int sl = 0; sl < 4; sl++) {
        int ci0 = (chunk << 5) + sl * 8;
        // vectorized staging: 8ci x 4 rows x 32 float4-segments = 1024 tasks (pow-2 math only)
        for (int t = tid; t < 1024; t += 256) {
            int seg = t & 31;
            int rid = t >> 5;
            int ci = rid >> 2, dr = rid & 3;
            int gh = h0 - 1 + dr;
            float4 v = make_float4(0.f, 0.f, 0.f, 0.f);
            if (gh >= 0 && gh < HFD)
                v = *(const float4*)&feat[(((size_t)((n << 8) + ci0 + ci)) << 14) + (gh << 7) + (seg << 2)];
            *(float4*)&in_t[ci][dr][4 + (seg << 2)] = v;
        }
        __syncthreads();
        for (int ci = 0; ci < 8; ci++) {
            int kbase = ((ci0 + ci) * 9) << 4;
#pragma unroll
            for (int r = 0; r < 3; r++) {
                float4 f4 = *(const float4*)&in_t[ci][row + r][4 + w0];   // aligned, conflict-free
                float left   = __shfl_up(f4.w, 1);
                float right1 = __shfl_down(f4.x, 1);
                if (qq == 0)  left   = 0.f;   // col -1: conv zero-pad
                if (qq == 31) right1 = 0.f;   // col 128: conv zero-pad
                double fv[6];
                fv[0] = (double)left;
                fv[1] = (double)f4.x; fv[2] = (double)f4.y;
                fv[3] = (double)f4.z; fv[4] = (double)f4.w;
                fv[5] = (double)right1;
#pragma unroll
                for (int s = 0; s < 3; s++) {
                    int widx = __builtin_amdgcn_readfirstlane(kbase + (((r * 3 + s) << 4) + (g << 2)));
                    const double* wp = E64 + widx;
                    double2 wv0 = *(const double2*)(wp);
                    double2 wv1 = *(const double2*)(wp + 2);
#pragma unroll
                    for (int px = 0; px < 4; px++) {
                        double f = fv[s + px];
                        acc[0][px] += wv0.x * f;
                        acc[1][px] += wv0.y * f;
                        acc[2][px] += wv1.x * f;
                        acc[3][px] += wv1.y * f;
                    }
                }
            }
        }
        __syncthreads();
    }
    int gpos = (n << 14) + ((h0 + row) << 7) + w0;
    double* base = PART + ((size_t)chunk << 20) + gpos;
#pragma unroll
    for (int cc = 0; cc < 4; cc++) {
        int c = g * 4 + cc;
        if (c < 15) {
            double2 s0; s0.x = acc[cc][0]; s0.y = acc[cc][1];
            double2 s1; s1.x = acc[cc][2]; s1.y = acc[cc][3];
            *(double2*)(base + (size_t)c * 65536) = s0;
            *(double2*)(base + (size_t)c * 65536 + 2) = s1;
        }
    }
}

// ---------------- K2: combine + fp64 decode -> KEY64, fused radix L0 histogram ----------------
__global__ __launch_bounds__(256) void k_findecode(const double* __restrict__ PART,
                                                   const double* __restrict__ EB64,
                                                   unsigned long long* __restrict__ KEY64,
                                                   uint32_t* __restrict__ HIST)
{
    __shared__ uint32_t h2[2048];
    int tid = threadIdx.x;
    for (int i = tid; i < 2048; i += 256) h2[i] = 0u;
    __syncthreads();
    int p = blockIdx.x * 256 + tid;   // 65536; block spans one image
    int n = p >> 14, pos = p & 16383;
    double L[15];
#pragma unroll
    for (int c = 0; c < 15; c++)
        L[c] = sum8(PART, (size_t)c * 65536 + p) + EB64[c];
#pragma unroll
    for (int a = 0; a < 3; a++) {
        double logit = L[a];
        double score = 1.0 / (1.0 + exp(-logit));
        int i = a * HW + pos;
        double c1, c2, c3, c4;
        decode_box(i, L[3 + a], L[6 + a], L[9 + a], L[12 + a], c1, c2, c3, c4);
        bool valid = (score > 0.3) && (c3 - c1 > 0.0) && (c4 - c2 > 0.0);
        unsigned long long key = valid ? ~((unsigned long long)__double_as_longlong(score)) : ~0ull;
        KEY64[(size_t)n * NPROP + i] = key;
        atomicAdd(&h2[(uint32_t)(key >> 53)], 1u);
    }
    __syncthreads();
    uint32_t* G = HIST + n * 2048;
    for (int i = tid; i < 2048; i += 256) {
        uint32_t v = h2[i];
        if (v) atomicAdd(&G[i], v);
    }
}

// ---------------- selection: grid-parallel radix passes with global state ----------------
__global__ __launch_bounds__(256) void k_hist(const unsigned long long* __restrict__ KEY64,
                                              const unsigned long long* __restrict__ PSPREF,
                                              uint32_t* __restrict__ HIST, int L)
{
    __shared__ uint32_t h[2048];
    int blk = blockIdx.x; int n = blk >> 4, sub = blk & 15;
    int tid = threadIdx.x;
    for (int i = tid; i < 2048; i += 256) h[i] = 0u;
    __syncthreads();
    int sh = 53 - 11 * L;
    unsigned long long pref = PSPREF[n];
    const unsigned long long* K = KEY64 + (size_t)n * NPROP + sub * 3072;
    for (int i = tid; i < 3072; i += 256) {
        unsigned long long k = K[i];
        if ((k >> (sh + 11)) == pref) atomicAdd(&h[(uint32_t)((k >> sh) & 2047ull)], 1u);
    }
    __syncthreads();
    uint32_t* G = HIST + n * 2048;
    for (int i = tid; i < 2048; i += 256) {
        uint32_t v = h[i];
        if (v) atomicAdd(&G[i], v);
    }
}

__global__ __launch_bounds__(256) void k_pick(uint32_t* __restrict__ HIST,
                                              unsigned long long* __restrict__ PSPREF,
                                              int* __restrict__ PSNEED)
{
    int n = blockIdx.x; int tid = threadIdx.x;
    __shared__ uint32_t hl[2048];
    __shared__ uint32_t psum[256];
    uint32_t* G = HIST + n * 2048;
    for (int i = tid; i < 2048; i += 256) hl[i] = G[i];
    __syncthreads();
    {
        uint32_t s = 0;
        for (int qq = 0; qq < 8; qq++) s += hl[tid * 8 + qq];
        psum[tid] = s;
    }
    __syncthreads();
    if (tid == 0) {
        int need = PSNEED[n];
        unsigned long long pref = PSPREF[n];
        uint32_t cum = 0; int g = 255;
        for (int t = 0; t < 256; t++) { uint32_t c = psum[t]; if (cum + c >= (uint32_t)need) { g = t; break; } cum += c; }
        int bsel = g * 8 + 7;
        for (int t = g * 8; t < g * 8 + 8; t++) { uint32_t c = hl[t]; if (cum + c >= (uint32_t)need) { bsel = t; break; } cum += c; }
        PSNEED[n] = need - (int)cum;
        PSPREF[n] = (pref << 11) | (unsigned long long)bsel;
    }
    __syncthreads();
    for (int i = tid; i < 2048; i += 256) G[i] = 0u;
}

__global__ __launch_bounds__(256) void k_collect(const unsigned long long* __restrict__ KEY64,
                                                 const unsigned long long* __restrict__ PSPREF,
                                                 uint32_t* __restrict__ CNT,
                                                 unsigned long long* __restrict__ CANDK,
                                                 uint32_t* __restrict__ CANDI)
{
    int blk = blockIdx.x; int n = blk >> 4, sub = blk & 15;
    int tid = threadIdx.x;
    unsigned long long pref44 = PSPREF[n];
    const unsigned long long* K = KEY64 + (size_t)n * NPROP;
    int base = sub * 3072;
    for (int i = tid; i < 3072; i += 256) {
        unsigned long long k = K[base + i];
        if (k != ~0ull && (k >> 20) <= pref44) {
            uint32_t p2 = atomicAdd(&CNT[n], 1u);
            if (p2 < 2048u) { CANDK[n * 2048 + p2] = k; CANDI[n * 2048 + p2] = (uint32_t)(base + i); }
        }
    }
}

__global__ __launch_bounds__(1024) void k_finalsel(const uint32_t* __restrict__ CNT,
                                                   const unsigned long long* __restrict__ CANDK,
                                                   const uint32_t* __restrict__ CANDI,
                                                   const double* __restrict__ PART,
                                                   const double* __restrict__ EB64,
                                                   unsigned long long* __restrict__ skeys,
                                                   double* __restrict__ bsort,
                                                   double* __restrict__ area)
{
    int n = blockIdx.x; int tid = threadIdx.x;
    __shared__ unsigned long long selk[2048];
    __shared__ uint32_t seli[2048];
    uint32_t cnt = CNT[n]; if (cnt > 2048u) cnt = 2048u;
    for (int t = tid; t < 2048; t += 1024) {
        if (t < (int)cnt) { selk[t] = CANDK[n * 2048 + t]; seli[t] = CANDI[n * 2048 + t]; }
        else { selk[t] = ~0ull; seli[t] = 0xFFFFFFFFu; }
    }
    __syncthreads();
    for (unsigned k2 = 2; k2 <= 2048; k2 <<= 1) {
        for (unsigned jx = k2 >> 1; jx > 0; jx >>= 1) {
            for (int t = tid; t < 2048; t += 1024) {
                unsigned ixj = (unsigned)t ^ jx;
                if (ixj > (unsigned)t) {
                    bool up = ((t & k2) == 0);
                    unsigned long long ka = selk[t], kb = selk[ixj];
                    uint32_t ia = seli[t], ib = seli[ixj];
                    bool agt = (ka > kb) || (ka == kb && ia > ib);
                    if (up ? agt : !agt) {
                        selk[t] = kb; selk[ixj] = ka;
                        seli[t] = ib; seli[ixj] = ia;
                    }
                }
            }
            __syncthreads();
        }
    }
    for (int t = tid; t < 2048; t += 1024) {
        bool valid = (t < PRE_NMS) && (selk[t] != ~0ull);
        if (t < PRE_NMS) skeys[(size_t)n * PRE_NMS + t] = valid ? selk[t] : ~0ull;
        double b0 = 0, b1 = 0, b2 = 0, b3 = 0;
        if (valid) {
            int i = (int)seli[t];
            int a = i >> 14, pos = i & 16383;
            size_t p = ((size_t)n << 14) + pos;
            double dx  = sum8(PART, (size_t)(3 + a)  * 65536 + p) + EB64[3 + a];
            double dy  = sum8(PART, (size_t)(6 + a)  * 65536 + p) + EB64[6 + a];
            double dwv = sum8(PART, (size_t)(9 + a)  * 65536 + p) + EB64[9 + a];
            double dhv = sum8(PART, (size_t)(12 + a) * 65536 + p) + EB64[12 + a];
            decode_box(i, dx, dy, dwv, dhv, b0, b1, b2, b3);
        }
        double* bs = bsort + (((size_t)(n * 2048 + t)) << 2);
        bs[0] = b0; bs[1] = b1; bs[2] = b2; bs[3] = b3;
        area[(size_t)n * 2048 + t] = fmax(b2 - b0, 0.0) * fmax(b3 - b1, 0.0);
    }
}

// ---------------- K4: pairwise IoU > 0.7 bitmask (32-row tiles, upper-triangle chunks only) ----------------
__global__ __launch_bounds__(256) void k_iou2(const double* __restrict__ bsort,
                                              const double* __restrict__ area,
                                              unsigned long long* __restrict__ mat)
{
    int blk = blockIdx.x; int n = blk >> 6; int rt = blk & 63;
    int tid = threadIdx.x;
    int r = tid >> 3, g = tid & 7;
    int i = rt * 32 + r;
    const double* bp = bsort + ((size_t)n * 2048 + i) * 4;
    double bx0 = bp[0], bx1_ = bp[1], bx2_ = bp[2], bx3 = bp[3];
    double ai = area[(size_t)n * 2048 + i];
    __shared__ double cbx[512][4];
    __shared__ double ca[512];
    for (int cc = 0; cc < 4; cc++) {
        if ((cc + 1) * 512 <= rt * 32) continue;
        __syncthreads();
        for (int idx = tid; idx < 512; idx += 256) {
            const double* sp = bsort + ((size_t)n * 2048 + cc * 512 + idx) * 4;
            cbx[idx][0] = sp[0]; cbx[idx][1] = sp[1]; cbx[idx][2] = sp[2]; cbx[idx][3] = sp[3];
            ca[idx] = area[(size_t)n * 2048 + cc * 512 + idx];
        }
        __syncthreads();
        unsigned long long wd = 0ull;
        for (int jb = 0; jb < 64; jb++) {
            int jr = (jb + g * 9) & 63;
            int jj = g * 64 + jr;
            double ix1 = fmax(bx0, cbx[jj][0]);
            double iy1 = fmax(bx1_, cbx[jj][1]);
            double ix2 = fmin(bx2_, cbx[jj][2]);
            double iy2 = fmin(bx3, cbx[jj][3]);
            double inter = fmax(ix2 - ix1, 0.0) * fmax(iy2 - iy1, 0.0);
            double den = fmax(ai + ca[jj] - inter, 1e-9);
            double iou = inter / den;
            if (iou > 0.7) wd |= (1ull << jr);
        }
        mat[((size_t)n * 2048 + i) * 32 + cc * 8 + g] = wd;
    }
}

// ---------------- K5: chunked NMS — early exit at 300 kept + parallel cross-chunk OR ----------------
__global__ __launch_bounds__(256) void k_nms3(const unsigned long long* __restrict__ skeys,
                                              const double* __restrict__ bsort,
                                              const unsigned long long* __restrict__ mat,
                                              float* __restrict__ out)
{
    int n = blockIdx.x; int tid = threadIdx.x;
    int lane = tid & 63;
    __shared__ unsigned long long rb[2][64][33];
    __shared__ unsigned long long sup_lds[32];
    __shared__ unsigned long long vb[32];
    __shared__ unsigned long long kbw[32];
    __shared__ int s_stop;
    float* dout = out + n * (POST_NMS * 5);
    for (int t = tid; t < POST_NMS * 5; t += 256) dout[t] = 0.f;
    if (tid < 32) { sup_lds[tid] = 0ull; kbw[tid] = 0ull; }
    if (tid == 0) s_stop = 0;
    if (tid < 64) {
        for (int i0 = 0; i0 < 2048; i0 += 64) {
            int i = i0 + lane;
            unsigned long long k = (i < PRE_NMS) ? skeys[(size_t)n * PRE_NMS + i] : ~0ull;
            unsigned long long m = __ballot(k != ~0ull);
            if (lane == 0) vb[i0 >> 6] = m;
        }
    }
    int r = tid >> 2, w0 = (tid & 3) * 8;
    {
        const unsigned long long* src = mat + ((size_t)n * 2048 + r) * 32 + w0;
        ulonglong2 a = *(const ulonglong2*)(src);
        ulonglong2 b = *(const ulonglong2*)(src + 2);
        ulonglong2 c2 = *(const ulonglong2*)(src + 4);
        ulonglong2 d = *(const ulonglong2*)(src + 6);
        unsigned long long* dst = &rb[0][r][w0];
        dst[0] = a.x; dst[1] = a.y; dst[2] = b.x; dst[3] = b.y;
        dst[4] = c2.x; dst[5] = c2.y; dst[6] = d.x; dst[7] = d.y;
    }
    __syncthreads();
    int total_kept = 0;
    for (int c = 0; c < 32; c++) {
        if (s_stop) break;
        int cur = c & 1, nxt = cur ^ 1;
        ulonglong2 pa, pb, pc, pd;
        bool pf = (c + 1 < 32);
        if (pf) {
            const unsigned long long* src = mat + ((size_t)n * 2048 + (c + 1) * 64 + r) * 32 + w0;
            pa = *(const ulonglong2*)(src);
            pb = *(const ulonglong2*)(src + 2);
            pc = *(const ulonglong2*)(src + 4);
            pd = *(const ulonglong2*)(src + 6);
        }
        if (tid < 64) {
            unsigned long long M = rb[cur][lane][c];
            unsigned long long supw = sup_lds[c];
            unsigned long long vbw = vb[c];
            unsigned long long km = 0ull;
#pragma unroll
            for (int ii = 0; ii < 64; ii++) {
                unsigned long long bit = 1ull << ii;
                if ((vbw & bit) && !(supw & bit)) {
                    km |= bit;
                    supw |= rl64(M, ii);
                }
            }
            if (lane == 0) {
                kbw[c] = km;
                total_kept += __popcll(km);
                if (total_kept >= POST_NMS) s_stop = 1;
            }
        }
        __syncthreads();
        {
            int w = tid & 31, g = tid >> 5;
            unsigned long long km2 = kbw[c];
            unsigned long long sub = (km2 >> (g * 8)) & 0xFFull;
            unsigned long long acc = 0ull;
            while (sub) {
                int bpos = __ffsll((long long)sub) - 1;
                sub &= sub - 1;
                acc |= rb[cur][g * 8 + bpos][w];
            }
            if (acc) atomicOr(&sup_lds[w], acc);
        }
        if (pf) {
            unsigned long long* dst = &rb[nxt][r][w0];
            dst[0] = pa.x; dst[1] = pa.y; dst[2] = pb.x; dst[3] = pb.y;
            dst[4] = pc.x; dst[5] = pc.y; dst[6] = pd.x; dst[7] = pd.y;
        }
        __syncthreads();
    }
    if (tid < 64) {
        int running = 0;
        for (int i0 = 0; i0 < 2048; i0 += 64) {
            int i = i0 + lane;
            bool kp = (i < PRE_NMS) && ((kbw[i >> 6] >> (i & 63)) & 1ull);
            unsigned long long m = __ballot(kp);
            if (kp) {
                int rk = running + __popcll(m & ((1ull << lane) - 1ull));
                if (rk < POST_NMS) {
                    const double* bp2 = bsort + ((size_t)n * 2048 + i) * 4;
                    unsigned long long k = skeys[(size_t)n * PRE_NMS + i];
                    double s = __longlong_as_double((long long)~k);
                    float* o = dout + rk * 5;
                    o[0] = (float)bp2[0]; o[1] = (float)bp2[1];
                    o[2] = (float)bp2[2]; o[3] = (float)bp2[3];
                    o[4] = (float)s;
                }
            }
            running += __popcll(m);
        }
    }
}

extern "C" void kernel_launch(void* const* d_in, const int* in_sizes, int n_in,
                              void* d_out, int out_size, void* d_ws, size_t ws_size,
                              hipStream_t stream) {
    (void)in_sizes; (void)n_in; (void)out_size; (void)ws_size;
    const float* feat   = (const float*)d_in[0];
    const float* conv_w = (const float*)d_in[1];
    const float* conv_b = (const float*)d_in[2];
    const float* det_w  = (const float*)d_in[3];
    const float* det_b  = (const float*)d_in[4];
    const float* reg_w  = (const float*)d_in[5];
    const float* reg_b  = (const float*)d_in[6];
    float* out = (float*)d_out;

    char* w = (char*)d_ws;
    double* E64 = (double*)w;                          w += (size_t)2304 * 16 * 8;
    double* EB64 = (double*)w;                         w += 128;
    double* PART = (double*)w;                         w += (size_t)8 << 23;                    // 67.1 MB
    unsigned long long* KEY64 = (unsigned long long*)w; w += (size_t)N_IMG * NPROP * 8;
    unsigned long long* PSPREF = (unsigned long long*)w; w += N_IMG * 8;
    int* PSNEED = (int*)w;                             w += 64;
    uint32_t* HIST = (uint32_t*)w;                     w += (size_t)N_IMG * 2048 * 4;
    uint32_t* CNT = (uint32_t*)w;                      w += 64;
    unsigned long long* CANDK = (unsigned long long*)w; w += (size_t)N_IMG * 2048 * 8;
    uint32_t* CANDI = (uint32_t*)w;                    w += (size_t)N_IMG * 2048 * 4;
    unsigned long long* SKEY = (unsigned long long*)w; w += (size_t)N_IMG * PRE_NMS * 8;
    double* BSORT = (double*)w;                        w += (size_t)N_IMG * 2048 * 4 * 8;
    double* AREA = (double*)w;                         w += (size_t)N_IMG * 2048 * 8;
    unsigned long long* MAT = (unsigned long long*)w;  w += (size_t)N_IMG * 2048 * 32 * 8;

    k_effw64<<<dim3(145), dim3(256), 0, stream>>>(conv_w, conv_b, det_w, det_b, reg_w, reg_b,
                                                  E64, EB64, PSPREF, PSNEED, HIST, CNT);
    k_conv64<<<dim3(2048), dim3(256), 0, stream>>>(feat, E64, PART);
    k_findecode<<<dim3(256), dim3(256), 0, stream>>>(PART, EB64, KEY64, HIST);
    k_pick<<<dim3(N_IMG), dim3(256), 0, stream>>>(HIST, PSPREF, PSNEED);     // L0
    for (int L = 1; L < 4; L++) {
        k_hist<<<dim3(64), dim3(256), 0, stream>>>(KEY64, PSPREF, HIST, L);
        k_pick<<<dim3(N_IMG), dim3(256), 0, stream>>>(HIST, PSPREF, PSNEED);
    }
    k_collect<<<dim3(64), dim3(256), 0, stream>>>(KEY64, PSPREF, CNT, CANDK, CANDI);
    k_finalsel<<<dim3(N_IMG), dim3(1024), 0, stream>>>(CNT, CANDK, CANDI, PART, EB64, SKEY, BSORT, AREA);
    k_iou2<<<dim3(N_IMG * 64), dim3(256), 0, stream>>>(BSORT, AREA, MAT);
    k_nms3<<<dim3(N_IMG), dim3(256), 0, stream>>>(SKEY, BSORT, MAT, out);
}

// Round 17
// 416.015 us; speedup vs baseline: 1.0295x; 1.0295x over previous
//
#include <hip/hip_runtime.h>
#include <hip/hip_bf16.h>
#include <hip/hip_fp16.h>
#include <stdint.h>
#include <math.h>

#define N_IMG 4
#define CIN 256
#define HFD 128
#define WFD 128
#define HW (HFD*WFD)        // 16384
#define NA 3
#define NPROP (NA*HW)       // 49152
#define PRE_NMS 2000
#define POST_NMS 300

__device__ __forceinline__ unsigned long long rl64(unsigned long long v, int i) {
    unsigned int lo = (unsigned int)__builtin_amdgcn_readlane((int)(unsigned int)v, i);
    unsigned int hi = (unsigned int)__builtin_amdgcn_readlane((int)(unsigned int)(v >> 32), i);
    return ((unsigned long long)hi << 32) | (unsigned long long)lo;
}

// PART layout: [chunk][c][p], chunk stride 1<<20 doubles, c stride 65536, p = (n<<14)+pos
__device__ __forceinline__ double sum4(const double* __restrict__ PART, size_t cp) {
    const size_t S = (size_t)1 << 20;
    return (PART[cp] + PART[cp + S]) + (PART[cp + 2 * S] + PART[cp + 3 * S]);
}

__device__ __forceinline__ void decode_box(int i, double dx, double dy, double dwv, double dhv,
                                           double& c1o, double& c2o, double& c3o, double& c4o) {
    int loc = i / 3, aa = i % 3;
    int hh = loc >> 7, wwi = loc & 127;
    double sx = (double)(wwi * 8), sy = (double)(hh * 8);
    double bx1 = (aa == 0) ? -91.0 : (aa == 1 ? -64.0 : -45.0);
    double by1 = (aa == 0) ? -45.0 : (aa == 1 ? -64.0 : -91.0);
    double x1 = sx + bx1, y1 = sy + by1, x2 = sx - bx1, y2 = sy - by1;
    double aw = x2 - x1, ahh = y2 - y1;
    double acx = y1 + aw * 0.5;   // (sic) swap, faithful to reference
    double acy = x1 + ahh * 0.5;  // (sic)
    double px = acx + dx * aw, py = acy + dy * ahh;
    double pw = aw * exp(dwv), ph = ahh * exp(dhv);
    double c1 = px - pw * 0.5, c2 = py - ph * 0.5, c3 = px + pw * 0.5, c4 = py + ph * 0.5;
    c1o = fmin(fmax(c1, 0.0), 1024.0);
    c2o = fmin(fmax(c2, 0.0), 1024.0);
    c3o = fmin(fmax(c3, 0.0), 1024.0);
    c4o = fmin(fmax(c4, 0.0), 1024.0);
}

// shared pick body (256-thread block): scan one image's 2048-bucket hist, update state, zero hist
__device__ __forceinline__ void pick_one(uint32_t* __restrict__ G,
                                         unsigned long long* __restrict__ PSPREF,
                                         int* __restrict__ PSNEED, int n,
                                         int tid, uint32_t* hl, uint32_t* psum) {
    for (int i = tid; i < 2048; i += 256) hl[i] = G[i];
    __syncthreads();
    {
        uint32_t s = 0;
        for (int qq = 0; qq < 8; qq++) s += hl[tid * 8 + qq];
        psum[tid] = s;
    }
    __syncthreads();
    if (tid == 0) {
        int need = PSNEED[n];
        unsigned long long pref = PSPREF[n];
        uint32_t cum = 0; int g = 255;
        for (int t = 0; t < 256; t++) { uint32_t c = psum[t]; if (cum + c >= (uint32_t)need) { g = t; break; } cum += c; }
        int bsel = g * 8 + 7;
        for (int t = g * 8; t < g * 8 + 8; t++) { uint32_t c = hl[t]; if (cum + c >= (uint32_t)need) { bsel = t; break; } cum += c; }
        PSNEED[n] = need - (int)cum;
        PSPREF[n] = (pref << 11) | (unsigned long long)bsel;
    }
    __syncthreads();
    for (int i = tid; i < 2048; i += 256) G[i] = 0u;
}

__device__ __forceinline__ void spin_until(uint32_t* __restrict__ ctr, uint32_t target, int tid) {
    if (tid == 0) {
        while (atomicAdd(ctr, 0u) < target) __builtin_amdgcn_s_sleep(1);
    }
    __syncthreads();
    __threadfence();
}

// ---------------- K0: effective fp64 weights + selection-state init ----------------
__global__ __launch_bounds__(256) void k_effw64(const float* __restrict__ cw, const float* __restrict__ cb,
                                                const float* __restrict__ dw_, const float* __restrict__ db_,
                                                const float* __restrict__ rw_, const float* __restrict__ rb_,
                                                double* __restrict__ E64, double* __restrict__ EB64,
                                                unsigned long long* __restrict__ PSPREF,
                                                int* __restrict__ PSNEED,
                                                uint32_t* __restrict__ HIST,
                                                uint32_t* __restrict__ CNT,
                                                uint32_t* __restrict__ DONE)
{
    int b = blockIdx.x;
    int tid = threadIdx.x;
    if (b < 144) {
        __shared__ float hwl[15][260];
        __shared__ float wt[256][16];
        int k0 = b * 16;
        for (int idx = tid; idx < 15 * 256; idx += 256) {
            int c = idx >> 8, co = idx & 255;
            hwl[c][co] = (c < 3) ? dw_[c * 256 + co] : rw_[(c - 3) * 256 + co];
        }
        for (int idx = tid; idx < 4096; idx += 256) {
            int co = idx >> 4, kk = idx & 15;
            wt[co][kk] = cw[co * 2304 + k0 + kk];
        }
        __syncthreads();
        int kk = tid >> 4, c = tid & 15;
        double s = 0.0;
        if (c < 15) {
#pragma unroll 4
            for (int co = 0; co < 256; co++) s += (double)hwl[c][co] * (double)wt[co][kk];
        }
        E64[(k0 + kk) * 16 + c] = s;
    } else {
        if (tid < 16) {
            int c = tid;
            double s = 0.0; double hb = 0.0;
            if (c < 15) {
                const float* hw = (c < 3) ? (dw_ + c * 256) : (rw_ + (c - 3) * 256);
                for (int co = 0; co < 256; co++) s += (double)hw[co] * (double)cb[co];
                hb = (double)((c < 3) ? db_[c] : rb_[c - 3]);
            }
            EB64[c] = s + hb;
        }
        for (int i = tid; i < N_IMG * 2048; i += 256) HIST[i] = 0u;
        if (tid < N_IMG) { PSPREF[tid] = 0ull; PSNEED[tid] = PRE_NMS; CNT[tid] = 0u; }
        if (tid < 8) DONE[tid] = 0u;
    }
}

// ---------------- K1: dense fused 15-output 3x3 conv, fp64 acc, 4-way ci-split, 2-row tiles ----------------
// grid 1024 = 4 img x 64 row-pairs x 4 chunks(64 ci); block 256
// Weights: wave-uniform s_load from global E64 (readfirstlane-forced), no LDS staging.
__global__ __launch_bounds__(256, 4) void k_conv64(const float* __restrict__ feat,
                                                   const double* __restrict__ E64,
                                                   double* __restrict__ PART)
{
    __shared__ float in_t[8][4][136];   // [ci][row h0-1..h0+2][4 + col]
    int b = blockIdx.x;
    int chunk = b & 3; int hp = (b >> 2) & 63; int n = b >> 8;
    int h0 = hp * 2;
    int tid = threadIdx.x;
    int q = tid & 63;
    int row = q >> 5, qq = q & 31, w0 = qq * 4;
    int g = tid >> 6;
    double acc[4][4];
#pragma unroll
    for (int cc = 0; cc < 4; cc++)
#pragma unroll
        for (int px = 0; px < 4; px++) acc[cc][px] = 0.0;

    for (int sl = 0; sl < 8; sl++) {
        int ci0 = (chunk << 6) + sl * 8;
        for (int t = tid; t < 1024; t += 256) {
            int seg = t & 31;
            int rid = t >> 5;
            int ci = rid >> 2, dr = rid & 3;
            int gh = h0 - 1 + dr;
            float4 v = make_float4(0.f, 0.f, 0.f, 0.f);
            if (gh >= 0 && gh < HFD)
                v = *(const float4*)&feat[(((size_t)((n << 8) + ci0 + ci)) << 14) + (gh << 7) + (seg << 2)];
            *(float4*)&in_t[ci][dr][4 + (seg << 2)] = v;
        }
        __syncthreads();
        for (int ci = 0; ci < 8; ci++) {
            int kbase = ((ci0 + ci) * 9) << 4;
#pragma unroll
            for (int r = 0; r < 3; r++) {
                float4 f4 = *(const float4*)&in_t[ci][row + r][4 + w0];   // aligned, conflict-free
                float left   = __shfl_up(f4.w, 1);
                float right1 = __shfl_down(f4.x, 1);
                if (qq == 0)  left   = 0.f;
                if (qq == 31) right1 = 0.f;
                double fv[6];
                fv[0] = (double)left;
                fv[1] = (double)f4.x; fv[2] = (double)f4.y;
                fv[3] = (double)f4.z; fv[4] = (double)f4.w;
                fv[5] = (double)right1;
#pragma unroll
                for (int s = 0; s < 3; s++) {
                    int widx = __builtin_amdgcn_readfirstlane(kbase + (((r * 3 + s) << 4) + (g << 2)));
                    const double* wp = E64 + widx;
                    double2 wv0 = *(const double2*)(wp);
                    double2 wv1 = *(const double2*)(wp + 2);
#pragma unroll
                    for (int px = 0; px < 4; px++) {
                        double f = fv[s + px];
                        acc[0][px] += wv0.x * f;
                        acc[1][px] += wv0.y * f;
                        acc[2][px] += wv1.x * f;
                        acc[3][px] += wv1.y * f;
                    }
                }
            }
        }
        __syncthreads();
    }
    int gpos = (n << 14) + ((h0 + row) << 7) + w0;
    double* base = PART + ((size_t)chunk << 20) + gpos;
#pragma unroll
    for (int cc = 0; cc < 4; cc++) {
        int c = g * 4 + cc;
        if (c < 15) {
            double2 s0; s0.x = acc[cc][0]; s0.y = acc[cc][1];
            double2 s1; s1.x = acc[cc][2]; s1.y = acc[cc][3];
            *(double2*)(base + (size_t)c * 65536) = s0;
            *(double2*)(base + (size_t)c * 65536 + 2) = s1;
        }
    }
}

// ---------------- K2: combine + decode -> KEY64 + L0 hist; 4 spin-wait pick blocks ----------------
// grid 260: blocks 0..255 decode+hist (block spans one image); 256..259 pick image (blk-256)
__global__ __launch_bounds__(256) void k_findecode(const double* __restrict__ PART,
                                                   const double* __restrict__ EB64,
                                                   unsigned long long* __restrict__ KEY64,
                                                   uint32_t* __restrict__ HIST,
                                                   uint32_t* __restrict__ DONE,
                                                   unsigned long long* __restrict__ PSPREF,
                                                   int* __restrict__ PSNEED)
{
    __shared__ uint32_t h2[2048];
    __shared__ uint32_t psum[256];
    int tid = threadIdx.x;
    int blk = blockIdx.x;
    if (blk < 256) {
        for (int i = tid; i < 2048; i += 256) h2[i] = 0u;
        __syncthreads();
        int p = blk * 256 + tid;
        int n = p >> 14, pos = p & 16383;
        double L[15];
#pragma unroll
        for (int c = 0; c < 15; c++)
            L[c] = sum4(PART, (size_t)c * 65536 + p) + EB64[c];
#pragma unroll
        for (int a = 0; a < 3; a++) {
            double logit = L[a];
            double score = 1.0 / (1.0 + exp(-logit));
            int i = a * HW + pos;
            double c1, c2, c3, c4;
            decode_box(i, L[3 + a], L[6 + a], L[9 + a], L[12 + a], c1, c2, c3, c4);
            bool valid = (score > 0.3) && (c3 - c1 > 0.0) && (c4 - c2 > 0.0);
            unsigned long long key = valid ? ~((unsigned long long)__double_as_longlong(score)) : ~0ull;
            KEY64[(size_t)n * NPROP + i] = key;
            atomicAdd(&h2[(uint32_t)(key >> 53)], 1u);
        }
        __syncthreads();
        uint32_t* G = HIST + n * 2048;
        for (int i = tid; i < 2048; i += 256) {
            uint32_t v = h2[i];
            if (v) atomicAdd(&G[i], v);
        }
        __threadfence();
        __syncthreads();
        if (tid == 0) atomicAdd(&DONE[0], 1u);
    } else {
        int n = blk - 256;
        spin_until(&DONE[0], 256u, tid);
        pick_one(HIST + n * 2048, PSPREF, PSNEED, n, tid, h2, psum);
    }
}

// ---------------- K3: radix pass L: 64 hist blocks + 4 spin-wait pick blocks ----------------
__global__ __launch_bounds__(256) void k_histpick(const unsigned long long* __restrict__ KEY64,
                                                  unsigned long long* __restrict__ PSPREF,
                                                  int* __restrict__ PSNEED,
                                                  uint32_t* __restrict__ HIST,
                                                  uint32_t* __restrict__ DONE, int L)
{
    __shared__ uint32_t h[2048];
    __shared__ uint32_t psum[256];
    int blk = blockIdx.x; int tid = threadIdx.x;
    if (blk < 64) {
        int n = blk >> 4, sub = blk & 15;
        for (int i = tid; i < 2048; i += 256) h[i] = 0u;
        __syncthreads();
        int sh = 53 - 11 * L;
        unsigned long long pref = PSPREF[n];
        const unsigned long long* K = KEY64 + (size_t)n * NPROP + sub * 3072;
        for (int i = tid; i < 3072; i += 256) {
            unsigned long long k = K[i];
            if ((k >> (sh + 11)) == pref) atomicAdd(&h[(uint32_t)((k >> sh) & 2047ull)], 1u);
        }
        __syncthreads();
        uint32_t* G = HIST + n * 2048;
        for (int i = tid; i < 2048; i += 256) {
            uint32_t v = h[i];
            if (v) atomicAdd(&G[i], v);
        }
        __threadfence();
        __syncthreads();
        if (tid == 0) atomicAdd(&DONE[L], 1u);
    } else {
        int n = blk - 64;
        spin_until(&DONE[L], 64u, tid);
        pick_one(HIST + n * 2048, PSPREF, PSNEED, n, tid, h, psum);
    }
}

// ---------------- K4: collect (64 blocks) + 4 spin-wait finalsel blocks ----------------
__global__ __launch_bounds__(1024) void k_collectsel(const unsigned long long* __restrict__ KEY64,
                                                     const unsigned long long* __restrict__ PSPREF,
                                                     uint32_t* __restrict__ CNT,
                                                     unsigned long long* __restrict__ CANDK,
                                                     uint32_t* __restrict__ CANDI,
                                                     uint32_t* __restrict__ DONE,
                                                     const double* __restrict__ PART,
                                                     const double* __restrict__ EB64,
                                                     unsigned long long* __restrict__ skeys,
                                                     double* __restrict__ bsort,
                                                     double* __restrict__ area)
{
    __shared__ unsigned long long selk[2048];
    __shared__ uint32_t seli[2048];
    int blk = blockIdx.x; int tid = threadIdx.x;
    if (blk < 64) {
        int n = blk >> 4, sub = blk & 15;
        unsigned long long pref44 = PSPREF[n];
        const unsigned long long* K = KEY64 + (size_t)n * NPROP;
        int base = sub * 3072;
        for (int i = tid; i < 3072; i += 1024) {
            unsigned long long k = K[base + i];
            if (k != ~0ull && (k >> 20) <= pref44) {
                uint32_t p2 = atomicAdd(&CNT[n], 1u);
                if (p2 < 2048u) { CANDK[n * 2048 + p2] = k; CANDI[n * 2048 + p2] = (uint32_t)(base + i); }
            }
        }
        __threadfence();
        __syncthreads();
        if (tid == 0) atomicAdd(&DONE[4], 1u);
        return;
    }
    int n = blk - 64;
    spin_until(&DONE[4], 64u, tid);
    uint32_t cnt = CNT[n]; if (cnt > 2048u) cnt = 2048u;
    for (int t = tid; t < 2048; t += 1024) {
        if (t < (int)cnt) { selk[t] = CANDK[n * 2048 + t]; seli[t] = CANDI[n * 2048 + t]; }
        else { selk[t] = ~0ull; seli[t] = 0xFFFFFFFFu; }
    }
    __syncthreads();
    for (unsigned k2 = 2; k2 <= 2048; k2 <<= 1) {
        for (unsigned jx = k2 >> 1; jx > 0; jx >>= 1) {
            for (int t = tid; t < 2048; t += 1024) {
                unsigned ixj = (unsigned)t ^ jx;
                if (ixj > (unsigned)t) {
                    bool up = ((t & k2) == 0);
                    unsigned long long ka = selk[t], kb = selk[ixj];
                    uint32_t ia = seli[t], ib = seli[ixj];
                    bool agt = (ka > kb) || (ka == kb && ia > ib);
                    if (up ? agt : !agt) {
                        selk[t] = kb; selk[ixj] = ka;
                        seli[t] = ib; seli[ixj] = ia;
                    }
                }
            }
            __syncthreads();
        }
    }
    for (int t = tid; t < 2048; t += 1024) {
        bool valid = (t < PRE_NMS) && (selk[t] != ~0ull);
        if (t < PRE_NMS) skeys[(size_t)n * PRE_NMS + t] = valid ? selk[t] : ~0ull;
        double b0 = 0, b1 = 0, b2 = 0, b3 = 0;
        if (valid) {
            int i = (int)seli[t];
            int a = i >> 14, pos = i & 16383;
            size_t p = ((size_t)n << 14) + pos;
            double dx  = sum4(PART, (size_t)(3 + a)  * 65536 + p) + EB64[3 + a];
            double dy  = sum4(PART, (size_t)(6 + a)  * 65536 + p) + EB64[6 + a];
            double dwv = sum4(PART, (size_t)(9 + a)  * 65536 + p) + EB64[9 + a];
            double dhv = sum4(PART, (size_t)(12 + a) * 65536 + p) + EB64[12 + a];
            decode_box(i, dx, dy, dwv, dhv, b0, b1, b2, b3);
        }
        double* bs = bsort + (((size_t)(n * 2048 + t)) << 2);
        bs[0] = b0; bs[1] = b1; bs[2] = b2; bs[3] = b3;
        area[(size_t)n * 2048 + t] = fmax(b2 - b0, 0.0) * fmax(b3 - b1, 0.0);
    }
}

// ---------------- K5: pairwise IoU > 0.7 bitmask (32-row tiles, upper-triangle chunks only) ----------------
__global__ __launch_bounds__(256) void k_iou2(const double* __restrict__ bsort,
                                              const double* __restrict__ area,
                                              unsigned long long* __restrict__ mat)
{
    int blk = blockIdx.x; int n = blk >> 6; int rt = blk & 63;
    int tid = threadIdx.x;
    int r = tid >> 3, g = tid & 7;
    int i = rt * 32 + r;
    const double* bp = bsort + ((size_t)n * 2048 + i) * 4;
    double bx0 = bp[0], bx1_ = bp[1], bx2_ = bp[2], bx3 = bp[3];
    double ai = area[(size_t)n * 2048 + i];
    __shared__ double cbx[512][4];
    __shared__ double ca[512];
    for (int cc = 0; cc < 4; cc++) {
        if ((cc + 1) * 512 <= rt * 32) continue;
        __syncthreads();
        for (int idx = tid; idx < 512; idx += 256) {
            const double* sp = bsort + ((size_t)n * 2048 + cc * 512 + idx) * 4;
            cbx[idx][0] = sp[0]; cbx[idx][1] = sp[1]; cbx[idx][2] = sp[2]; cbx[idx][3] = sp[3];
            ca[idx] = area[(size_t)n * 2048 + cc * 512 + idx];
        }
        __syncthreads();
        unsigned long long wd = 0ull;
        for (int jb = 0; jb < 64; jb++) {
            int jr = (jb + g * 9) & 63;
            int jj = g * 64 + jr;
            double ix1 = fmax(bx0, cbx[jj][0]);
            double iy1 = fmax(bx1_, cbx[jj][1]);
            double ix2 = fmin(bx2_, cbx[jj][2]);
            double iy2 = fmin(bx3, cbx[jj][3]);
            double inter = fmax(ix2 - ix1, 0.0) * fmax(iy2 - iy1, 0.0);
            double den = fmax(ai + ca[jj] - inter, 1e-9);
            double iou = inter / den;
            if (iou > 0.7) wd |= (1ull << jr);
        }
        mat[((size_t)n * 2048 + i) * 32 + cc * 8 + g] = wd;
    }
}

// ---------------- K6: chunked NMS — early exit at 300 kept + parallel cross-chunk OR ----------------
__global__ __launch_bounds__(256) void k_nms3(const unsigned long long* __restrict__ skeys,
                                              const double* __restrict__ bsort,
                                              const unsigned long long* __restrict__ mat,
                                              float* __restrict__ out)
{
    int n = blockIdx.x; int tid = threadIdx.x;
    int lane = tid & 63;
    __shared__ unsigned long long rb[2][64][33];
    __shared__ unsigned long long sup_lds[32];
    __shared__ unsigned long long vb[32];
    __shared__ unsigned long long kbw[32];
    __shared__ int s_stop;
    float* dout = out + n * (POST_NMS * 5);
    for (int t = tid; t < POST_NMS * 5; t += 256) dout[t] = 0.f;
    if (tid < 32) { sup_lds[tid] = 0ull; kbw[tid] = 0ull; }
    if (tid == 0) s_stop = 0;
    if (tid < 64) {
        for (int i0 = 0; i0 < 2048; i0 += 64) {
            int i = i0 + lane;
            unsigned long long k = (i < PRE_NMS) ? skeys[(size_t)n * PRE_NMS + i] : ~0ull;
            unsigned long long m = __ballot(k != ~0ull);
            if (lane == 0) vb[i0 >> 6] = m;
        }
    }
    int r = tid >> 2, w0 = (tid & 3) * 8;
    {
        const unsigned long long* src = mat + ((size_t)n * 2048 + r) * 32 + w0;
        ulonglong2 a = *(const ulonglong2*)(src);
        ulonglong2 b = *(const ulonglong2*)(src + 2);
        ulonglong2 c2 = *(const ulonglong2*)(src + 4);
        ulonglong2 d = *(const ulonglong2*)(src + 6);
        unsigned long long* dst = &rb[0][r][w0];
        dst[0] = a.x; dst[1] = a.y; dst[2] = b.x; dst[3] = b.y;
        dst[4] = c2.x; dst[5] = c2.y; dst[6] = d.x; dst[7] = d.y;
    }
    __syncthreads();
    int total_kept = 0;
    for (int c = 0; c < 32; c++) {
        if (s_stop) break;
        int cur = c & 1, nxt = cur ^ 1;
        ulonglong2 pa, pb, pc, pd;
        bool pf = (c + 1 < 32);
        if (pf) {
            const unsigned long long* src = mat + ((size_t)n * 2048 + (c + 1) * 64 + r) * 32 + w0;
            pa = *(const ulonglong2*)(src);
            pb = *(const ulonglong2*)(src + 2);
            pc = *(const ulonglong2*)(src + 4);
            pd = *(const ulonglong2*)(src + 6);
        }
        if (tid < 64) {
            unsigned long long M = rb[cur][lane][c];
            unsigned long long supw = sup_lds[c];
            unsigned long long vbw = vb[c];
            unsigned long long km = 0ull;
#pragma unroll
            for (int ii = 0; ii < 64; ii++) {
                unsigned long long bit = 1ull << ii;
                if ((vbw & bit) && !(supw & bit)) {
                    km |= bit;
                    supw |= rl64(M, ii);
                }
            }
            if (lane == 0) {
                kbw[c] = km;
                total_kept += __popcll(km);
                if (total_kept >= POST_NMS) s_stop = 1;
            }
        }
        __syncthreads();
        {
            int w = tid & 31, g = tid >> 5;
            unsigned long long km2 = kbw[c];
            unsigned long long sub = (km2 >> (g * 8)) & 0xFFull;
            unsigned long long acc = 0ull;
            while (sub) {
                int bpos = __ffsll((long long)sub) - 1;
                sub &= sub - 1;
                acc |= rb[cur][g * 8 + bpos][w];
            }
            if (acc) atomicOr(&sup_lds[w], acc);
        }
        if (pf) {
            unsigned long long* dst = &rb[nxt][r][w0];
            dst[0] = pa.x; dst[1] = pa.y; dst[2] = pb.x; dst[3] = pb.y;
            dst[4] = pc.x; dst[5] = pc.y; dst[6] = pd.x; dst[7] = pd.y;
        }
        __syncthreads();
    }
    if (tid < 64) {
        int running = 0;
        for (int i0 = 0; i0 < 2048; i0 += 64) {
            int i = i0 + lane;
            bool kp = (i < PRE_NMS) && ((kbw[i >> 6] >> (i & 63)) & 1ull);
            unsigned long long m = __ballot(kp);
            if (kp) {
                int rk = running + __popcll(m & ((1ull << lane) - 1ull));
                if (rk < POST_NMS) {
                    const double* bp2 = bsort + ((size_t)n * 2048 + i) * 4;
                    unsigned long long k = skeys[(size_t)n * PRE_NMS + i];
                    double s = __longlong_as_double((long long)~k);
                    float* o = dout + rk * 5;
                    o[0] = (float)bp2[0]; o[1] = (float)bp2[1];
                    o[2] = (float)bp2[2]; o[3] = (float)bp2[3];
                    o[4] = (float)s;
                }
            }
            running += __popcll(m);
        }
    }
}

extern "C" void kernel_launch(void* const* d_in, const int* in_sizes, int n_in,
                              void* d_out, int out_size, void* d_ws, size_t ws_size,
                              hipStream_t stream) {
    (void)in_sizes; (void)n_in; (void)out_size; (void)ws_size;
    const float* feat   = (const float*)d_in[0];
    const float* conv_w = (const float*)d_in[1];
    const float* conv_b = (const float*)d_in[2];
    const float* det_w  = (const float*)d_in[3];
    const float* det_b  = (const float*)d_in[4];
    const float* reg_w  = (const float*)d_in[5];
    const float* reg_b  = (const float*)d_in[6];
    float* out = (float*)d_out;

    char* w = (char*)d_ws;
    double* E64 = (double*)w;                          w += (size_t)2304 * 16 * 8;
    double* EB64 = (double*)w;                         w += 128;
    double* PART = (double*)w;                         w += (size_t)4 << 23;                    // 33.6 MB
    unsigned long long* KEY64 = (unsigned long long*)w; w += (size_t)N_IMG * NPROP * 8;
    unsigned long long* PSPREF = (unsigned long long*)w; w += N_IMG * 8;
    int* PSNEED = (int*)w;                             w += 64;
    uint32_t* HIST = (uint32_t*)w;                     w += (size_t)N_IMG * 2048 * 4;
    uint32_t* CNT = (uint32_t*)w;                      w += 64;
    uint32_t* DONE = (uint32_t*)w;                     w += 64;
    unsigned long long* CANDK = (unsigned long long*)w; w += (size_t)N_IMG * 2048 * 8;
    uint32_t* CANDI = (uint32_t*)w;                    w += (size_t)N_IMG * 2048 * 4;
    unsigned long long* SKEY = (unsigned long long*)w; w += (size_t)N_IMG * PRE_NMS * 8;
    double* BSORT = (double*)w;                        w += (size_t)N_IMG * 2048 * 4 * 8;
    double* AREA = (double*)w;                         w += (size_t)N_IMG * 2048 * 8;
    unsigned long long* MAT = (unsigned long long*)w;  w += (size_t)N_IMG * 2048 * 32 * 8;

    k_effw64<<<dim3(145), dim3(256), 0, stream>>>(conv_w, conv_b, det_w, det_b, reg_w, reg_b,
                                                  E64, EB64, PSPREF, PSNEED, HIST, CNT, DONE);
    k_conv64<<<dim3(1024), dim3(256), 0, stream>>>(feat, E64, PART);
    k_findecode<<<dim3(260), dim3(256), 0, stream>>>(PART, EB64, KEY64, HIST, DONE, PSPREF, PSNEED);
    for (int L = 1; L < 4; L++) {
        k_histpick<<<dim3(68), dim3(256), 0, stream>>>(KEY64, PSPREF, PSNEED, HIST, DONE, L);
    }
    k_collectsel<<<dim3(68), dim3(1024), 0, stream>>>(KEY64, PSPREF, CNT, CANDK, CANDI, DONE,
                                                      PART, EB64, SKEY, BSORT, AREA);
    k_iou2<<<dim3(N_IMG * 64), dim3(256), 0, stream>>>(BSORT, AREA, MAT);
    k_nms3<<<dim3(N_IMG), dim3(256), 0, stream>>>(SKEY, BSORT, MAT, out);
}

// Round 18
// 410.714 us; speedup vs baseline: 1.0427x; 1.0129x over previous
//
#include <hip/hip_runtime.h>
#include <hip/hip_bf16.h>
#include <hip/hip_fp16.h>
#include <stdint.h>
#include <math.h>

#define N_IMG 4
#define CIN 256
#define HFD 128
#define WFD 128
#define HW (HFD*WFD)        // 16384
#define NA 3
#define NPROP (NA*HW)       // 49152
#define PRE_NMS 2000
#define POST_NMS 300

__device__ __forceinline__ unsigned long long rl64(unsigned long long v, int i) {
    unsigned int lo = (unsigned int)__builtin_amdgcn_readlane((int)(unsigned int)v, i);
    unsigned int hi = (unsigned int)__builtin_amdgcn_readlane((int)(unsigned int)(v >> 32), i);
    return ((unsigned long long)hi << 32) | (unsigned long long)lo;
}

// PART layout: [chunk][c][p], chunk stride 1<<20 doubles, c stride 65536, p = (n<<14)+pos
__device__ __forceinline__ double sum4(const double* __restrict__ PART, size_t cp) {
    const size_t S = (size_t)1 << 20;
    return (PART[cp] + PART[cp + S]) + (PART[cp + 2 * S] + PART[cp + 3 * S]);
}

__device__ __forceinline__ void decode_box(int i, double dx, double dy, double dwv, double dhv,
                                           double& c1o, double& c2o, double& c3o, double& c4o) {
    int loc = i / 3, aa = i % 3;
    int hh = loc >> 7, wwi = loc & 127;
    double sx = (double)(wwi * 8), sy = (double)(hh * 8);
    double bx1 = (aa == 0) ? -91.0 : (aa == 1 ? -64.0 : -45.0);
    double by1 = (aa == 0) ? -45.0 : (aa == 1 ? -64.0 : -91.0);
    double x1 = sx + bx1, y1 = sy + by1, x2 = sx - bx1, y2 = sy - by1;
    double aw = x2 - x1, ahh = y2 - y1;
    double acx = y1 + aw * 0.5;   // (sic) swap, faithful to reference
    double acy = x1 + ahh * 0.5;  // (sic)
    double px = acx + dx * aw, py = acy + dy * ahh;
    double pw = aw * exp(dwv), ph = ahh * exp(dhv);
    double c1 = px - pw * 0.5, c2 = py - ph * 0.5, c3 = px + pw * 0.5, c4 = py + ph * 0.5;
    c1o = fmin(fmax(c1, 0.0), 1024.0);
    c2o = fmin(fmax(c2, 0.0), 1024.0);
    c3o = fmin(fmax(c3, 0.0), 1024.0);
    c4o = fmin(fmax(c4, 0.0), 1024.0);
}

// derive the running (prefix,need) by scanning stored histogram levels 0..levels-1.
// Deterministic integer recurrence -> identical result in every calling block.
// Block must be 256 threads.
__device__ __forceinline__ unsigned long long derive_pref(const uint32_t* __restrict__ HB,
                                                          int levels, int tid,
                                                          uint32_t* hl, uint32_t* psum,
                                                          uint32_t* s_bsel, int* s_need) {
    unsigned long long pref = 0ull;
    if (tid == 0) *s_need = PRE_NMS;
    __syncthreads();
    for (int lv = 0; lv < levels; lv++) {
        const uint32_t* G = HB + lv * 2048;
        for (int i = tid; i < 2048; i += 256) hl[i] = G[i];
        __syncthreads();
        {
            uint32_t s = 0;
            for (int qq = 0; qq < 8; qq++) s += hl[tid * 8 + qq];
            psum[tid] = s;
        }
        __syncthreads();
        if (tid == 0) {
            int need = *s_need;
            uint32_t cum = 0; int g = 255;
            for (int t = 0; t < 256; t++) { uint32_t c = psum[t]; if (cum + c >= (uint32_t)need) { g = t; break; } cum += c; }
            int bsel = g * 8 + 7;
            for (int t = g * 8; t < g * 8 + 8; t++) { uint32_t c = hl[t]; if (cum + c >= (uint32_t)need) { bsel = t; break; } cum += c; }
            *s_need = need - (int)cum;
            *s_bsel = (uint32_t)bsel;
        }
        __syncthreads();
        pref = (pref << 11) | (unsigned long long)(*s_bsel);
        __syncthreads();
    }
    return pref;
}

// ---------------- K0: effective fp64 weights + selection-state init ----------------
__global__ __launch_bounds__(256) void k_effw64(const float* __restrict__ cw, const float* __restrict__ cb,
                                                const float* __restrict__ dw_, const float* __restrict__ db_,
                                                const float* __restrict__ rw_, const float* __restrict__ rb_,
                                                double* __restrict__ E64, double* __restrict__ EB64,
                                                uint32_t* __restrict__ HISTS,
                                                uint32_t* __restrict__ CNT)
{
    int b = blockIdx.x;
    int tid = threadIdx.x;
    if (b < 144) {
        __shared__ float hwl[15][260];
        __shared__ float wt[256][16];
        int k0 = b * 16;
        for (int idx = tid; idx < 15 * 256; idx += 256) {
            int c = idx >> 8, co = idx & 255;
            hwl[c][co] = (c < 3) ? dw_[c * 256 + co] : rw_[(c - 3) * 256 + co];
        }
        for (int idx = tid; idx < 4096; idx += 256) {
            int co = idx >> 4, kk = idx & 15;
            wt[co][kk] = cw[co * 2304 + k0 + kk];
        }
        __syncthreads();
        int kk = tid >> 4, c = tid & 15;
        double s = 0.0;
        if (c < 15) {
#pragma unroll 4
            for (int co = 0; co < 256; co++) s += (double)hwl[c][co] * (double)wt[co][kk];
        }
        E64[(k0 + kk) * 16 + c] = s;
    } else {
        if (tid < 16) {
            int c = tid;
            double s = 0.0; double hb = 0.0;
            if (c < 15) {
                const float* hw = (c < 3) ? (dw_ + c * 256) : (rw_ + (c - 3) * 256);
                for (int co = 0; co < 256; co++) s += (double)hw[co] * (double)cb[co];
                hb = (double)((c < 3) ? db_[c] : rb_[c - 3]);
            }
            EB64[c] = s + hb;
        }
        for (int i = tid; i < N_IMG * 4 * 2048; i += 256) HISTS[i] = 0u;
        if (tid < N_IMG) CNT[tid] = 0u;
    }
}

// ---------------- K1: dense fused 15-output 3x3 conv, fp64 acc, 4-way ci-split, 2-row tiles ----------------
// grid 1024 = 4 img x 64 row-pairs x 4 chunks(64 ci); block 256
// Weights: wave-uniform s_load from global E64 (readfirstlane-forced), no LDS staging.
__global__ __launch_bounds__(256, 4) void k_conv64(const float* __restrict__ feat,
                                                   const double* __restrict__ E64,
                                                   double* __restrict__ PART)
{
    __shared__ float in_t[8][4][136];   // [ci][row h0-1..h0+2][4 + col]
    int b = blockIdx.x;
    int chunk = b & 3; int hp = (b >> 2) & 63; int n = b >> 8;
    int h0 = hp * 2;
    int tid = threadIdx.x;
    int q = tid & 63;
    int row = q >> 5, qq = q & 31, w0 = qq * 4;
    int g = tid >> 6;
    double acc[4][4];
#pragma unroll
    for (int cc = 0; cc < 4; cc++)
#pragma unroll
        for (int px = 0; px < 4; px++) acc[cc][px] = 0.0;

    for (int sl = 0; sl < 8; sl++) {
        int ci0 = (chunk << 6) + sl * 8;
        for (int t = tid; t < 1024; t += 256) {
            int seg = t & 31;
            int rid = t >> 5;
            int ci = rid >> 2, dr = rid & 3;
            int gh = h0 - 1 + dr;
            float4 v = make_float4(0.f, 0.f, 0.f, 0.f);
            if (gh >= 0 && gh < HFD)
                v = *(const float4*)&feat[(((size_t)((n << 8) + ci0 + ci)) << 14) + (gh << 7) + (seg << 2)];
            *(float4*)&in_t[ci][dr][4 + (seg << 2)] = v;
        }
        __syncthreads();
        for (int ci = 0; ci < 8; ci++) {
            int kbase = ((ci0 + ci) * 9) << 4;
#pragma unroll
            for (int r = 0; r < 3; r++) {
                float4 f4 = *(const float4*)&in_t[ci][row + r][4 + w0];   // aligned, conflict-free
                float left   = __shfl_up(f4.w, 1);
                float right1 = __shfl_down(f4.x, 1);
                if (qq == 0)  left   = 0.f;
                if (qq == 31) right1 = 0.f;
                double fv[6];
                fv[0] = (double)left;
                fv[1] = (double)f4.x; fv[2] = (double)f4.y;
                fv[3] = (double)f4.z; fv[4] = (double)f4.w;
                fv[5] = (double)right1;
#pragma unroll
                for (int s = 0; s < 3; s++) {
                    int widx = __builtin_amdgcn_readfirstlane(kbase + (((r * 3 + s) << 4) + (g << 2)));
                    const double* wp = E64 + widx;
                    double2 wv0 = *(const double2*)(wp);
                    double2 wv1 = *(const double2*)(wp + 2);
#pragma unroll
                    for (int px = 0; px < 4; px++) {
                        double f = fv[s + px];
                        acc[0][px] += wv0.x * f;
                        acc[1][px] += wv0.y * f;
                        acc[2][px] += wv1.x * f;
                        acc[3][px] += wv1.y * f;
                    }
                }
            }
        }
        __syncthreads();
    }
    int gpos = (n << 14) + ((h0 + row) << 7) + w0;
    double* base = PART + ((size_t)chunk << 20) + gpos;
#pragma unroll
    for (int cc = 0; cc < 4; cc++) {
        int c = g * 4 + cc;
        if (c < 15) {
            double2 s0; s0.x = acc[cc][0]; s0.y = acc[cc][1];
            double2 s1; s1.x = acc[cc][2]; s1.y = acc[cc][3];
            *(double2*)(base + (size_t)c * 65536) = s0;
            *(double2*)(base + (size_t)c * 65536 + 2) = s1;
        }
    }
}

// ---------------- K2: combine + fp64 decode -> KEY64, fused radix L0 histogram ----------------
__global__ __launch_bounds__(256) void k_findecode(const double* __restrict__ PART,
                                                   const double* __restrict__ EB64,
                                                   unsigned long long* __restrict__ KEY64,
                                                   uint32_t* __restrict__ HISTS)
{
    __shared__ uint32_t h2[2048];
    int tid = threadIdx.x;
    for (int i = tid; i < 2048; i += 256) h2[i] = 0u;
    __syncthreads();
    int p = blockIdx.x * 256 + tid;   // 65536; block spans one image
    int n = p >> 14, pos = p & 16383;
    double L[15];
#pragma unroll
    for (int c = 0; c < 15; c++)
        L[c] = sum4(PART, (size_t)c * 65536 + p) + EB64[c];
#pragma unroll
    for (int a = 0; a < 3; a++) {
        double logit = L[a];
        double score = 1.0 / (1.0 + exp(-logit));
        int i = a * HW + pos;
        double c1, c2, c3, c4;
        decode_box(i, L[3 + a], L[6 + a], L[9 + a], L[12 + a], c1, c2, c3, c4);
        bool valid = (score > 0.3) && (c3 - c1 > 0.0) && (c4 - c2 > 0.0);
        unsigned long long key = valid ? ~((unsigned long long)__double_as_longlong(score)) : ~0ull;
        KEY64[(size_t)n * NPROP + i] = key;
        atomicAdd(&h2[(uint32_t)(key >> 53)], 1u);
    }
    __syncthreads();
    uint32_t* G = HISTS + n * 8192;   // level 0
    for (int i = tid; i < 2048; i += 256) {
        uint32_t v = h2[i];
        if (v) atomicAdd(&G[i], v);
    }
}

// ---------------- K3: radix pass L (1..3): derive prefix from stored levels, hist into level L ----------------
__global__ __launch_bounds__(256) void k_hist(const unsigned long long* __restrict__ KEY64,
                                              uint32_t* __restrict__ HISTS, int L)
{
    __shared__ uint32_t h[2048];
    __shared__ uint32_t psum[256];
    __shared__ uint32_t s_bsel;
    __shared__ int s_need;
    int blk = blockIdx.x; int n = blk >> 4, sub = blk & 15;
    int tid = threadIdx.x;
    unsigned long long pref = derive_pref(HISTS + n * 8192, L, tid, h, psum, &s_bsel, &s_need);
    for (int i = tid; i < 2048; i += 256) h[i] = 0u;
    __syncthreads();
    int sh = 53 - 11 * L;
    const unsigned long long* K = KEY64 + (size_t)n * NPROP + sub * 3072;
    for (int i = tid; i < 3072; i += 256) {
        unsigned long long k = K[i];
        if ((k >> (sh + 11)) == pref) atomicAdd(&h[(uint32_t)((k >> sh) & 2047ull)], 1u);
    }
    __syncthreads();
    uint32_t* G = HISTS + n * 8192 + L * 2048;
    for (int i = tid; i < 2048; i += 256) {
        uint32_t v = h[i];
        if (v) atomicAdd(&G[i], v);
    }
}

// ---------------- K4: collect boundary candidates (derive full 44-bit prefix locally) ----------------
__global__ __launch_bounds__(256) void k_collect(const unsigned long long* __restrict__ KEY64,
                                                 uint32_t* __restrict__ HISTS,
                                                 uint32_t* __restrict__ CNT,
                                                 unsigned long long* __restrict__ CANDK,
                                                 uint32_t* __restrict__ CANDI)
{
    __shared__ uint32_t h[2048];
    __shared__ uint32_t psum[256];
    __shared__ uint32_t s_bsel;
    __shared__ int s_need;
    int blk = blockIdx.x; int n = blk >> 4, sub = blk & 15;
    int tid = threadIdx.x;
    unsigned long long pref44 = derive_pref(HISTS + n * 8192, 4, tid, h, psum, &s_bsel, &s_need);
    const unsigned long long* K = KEY64 + (size_t)n * NPROP;
    int base = sub * 3072;
    for (int i = tid; i < 3072; i += 256) {
        unsigned long long k = K[base + i];
        if (k != ~0ull && (k >> 20) <= pref44) {
            uint32_t p2 = atomicAdd(&CNT[n], 1u);
            if (p2 < 2048u) { CANDK[n * 2048 + p2] = k; CANDI[n * 2048 + p2] = (uint32_t)(base + i); }
        }
    }
}

__global__ __launch_bounds__(1024) void k_finalsel(const uint32_t* __restrict__ CNT,
                                                   const unsigned long long* __restrict__ CANDK,
                                                   const uint32_t* __restrict__ CANDI,
                                                   const double* __restrict__ PART,
                                                   const double* __restrict__ EB64,
                                                   unsigned long long* __restrict__ skeys,
                                                   double* __restrict__ bsort,
                                                   double* __restrict__ area)
{
    int n = blockIdx.x; int tid = threadIdx.x;
    __shared__ unsigned long long selk[2048];
    __shared__ uint32_t seli[2048];
    uint32_t cnt = CNT[n]; if (cnt > 2048u) cnt = 2048u;
    for (int t = tid; t < 2048; t += 1024) {
        if (t < (int)cnt) { selk[t] = CANDK[n * 2048 + t]; seli[t] = CANDI[n * 2048 + t]; }
        else { selk[t] = ~0ull; seli[t] = 0xFFFFFFFFu; }
    }
    __syncthreads();
    for (unsigned k2 = 2; k2 <= 2048; k2 <<= 1) {
        for (unsigned jx = k2 >> 1; jx > 0; jx >>= 1) {
            for (int t = tid; t < 2048; t += 1024) {
                unsigned ixj = (unsigned)t ^ jx;
                if (ixj > (unsigned)t) {
                    bool up = ((t & k2) == 0);
                    unsigned long long ka = selk[t], kb = selk[ixj];
                    uint32_t ia = seli[t], ib = seli[ixj];
                    bool agt = (ka > kb) || (ka == kb && ia > ib);
                    if (up ? agt : !agt) {
                        selk[t] = kb; selk[ixj] = ka;
                        seli[t] = ib; seli[ixj] = ia;
                    }
                }
            }
            __syncthreads();
        }
    }
    for (int t = tid; t < 2048; t += 1024) {
        bool valid = (t < PRE_NMS) && (selk[t] != ~0ull);
        if (t < PRE_NMS) skeys[(size_t)n * PRE_NMS + t] = valid ? selk[t] : ~0ull;
        double b0 = 0, b1 = 0, b2 = 0, b3 = 0;
        if (valid) {
            int i = (int)seli[t];
            int a = i >> 14, pos = i & 16383;
            size_t p = ((size_t)n << 14) + pos;
            double dx  = sum4(PART, (size_t)(3 + a)  * 65536 + p) + EB64[3 + a];
            double dy  = sum4(PART, (size_t)(6 + a)  * 65536 + p) + EB64[6 + a];
            double dwv = sum4(PART, (size_t)(9 + a)  * 65536 + p) + EB64[9 + a];
            double dhv = sum4(PART, (size_t)(12 + a) * 65536 + p) + EB64[12 + a];
            decode_box(i, dx, dy, dwv, dhv, b0, b1, b2, b3);
        }
        double* bs = bsort + (((size_t)(n * 2048 + t)) << 2);
        bs[0] = b0; bs[1] = b1; bs[2] = b2; bs[3] = b3;
        area[(size_t)n * 2048 + t] = fmax(b2 - b0, 0.0) * fmax(b3 - b1, 0.0);
    }
}

// ---------------- K5: pairwise IoU > 0.7 bitmask (32-row tiles, upper-triangle chunks only) ----------------
__global__ __launch_bounds__(256) void k_iou2(const double* __restrict__ bsort,
                                              const double* __restrict__ area,
                                              unsigned long long* __restrict__ mat)
{
    int blk = blockIdx.x; int n = blk >> 6; int rt = blk & 63;
    int tid = threadIdx.x;
    int r = tid >> 3, g = tid & 7;
    int i = rt * 32 + r;
    const double* bp = bsort + ((size_t)n * 2048 + i) * 4;
    double bx0 = bp[0], bx1_ = bp[1], bx2_ = bp[2], bx3 = bp[3];
    double ai = area[(size_t)n * 2048 + i];
    __shared__ double cbx[512][4];
    __shared__ double ca[512];
    for (int cc = 0; cc < 4; cc++) {
        if ((cc + 1) * 512 <= rt * 32) continue;
        __syncthreads();
        for (int idx = tid; idx < 512; idx += 256) {
            const double* sp = bsort + ((size_t)n * 2048 + cc * 512 + idx) * 4;
            cbx[idx][0] = sp[0]; cbx[idx][1] = sp[1]; cbx[idx][2] = sp[2]; cbx[idx][3] = sp[3];
            ca[idx] = area[(size_t)n * 2048 + cc * 512 + idx];
        }
        __syncthreads();
        unsigned long long wd = 0ull;
        for (int jb = 0; jb < 64; jb++) {
            int jr = (jb + g * 9) & 63;
            int jj = g * 64 + jr;
            double ix1 = fmax(bx0, cbx[jj][0]);
            double iy1 = fmax(bx1_, cbx[jj][1]);
            double ix2 = fmin(bx2_, cbx[jj][2]);
            double iy2 = fmin(bx3, cbx[jj][3]);
            double inter = fmax(ix2 - ix1, 0.0) * fmax(iy2 - iy1, 0.0);
            double den = fmax(ai + ca[jj] - inter, 1e-9);
            double iou = inter / den;
            if (iou > 0.7) wd |= (1ull << jr);
        }
        mat[((size_t)n * 2048 + i) * 32 + cc * 8 + g] = wd;
    }
}

// ---------------- K6: chunked NMS — early exit at 300 kept + parallel cross-chunk OR ----------------
__global__ __launch_bounds__(256) void k_nms3(const unsigned long long* __restrict__ skeys,
                                              const double* __restrict__ bsort,
                                              const unsigned long long* __restrict__ mat,
                                              float* __restrict__ out)
{
    int n = blockIdx.x; int tid = threadIdx.x;
    int lane = tid & 63;
    __shared__ unsigned long long rb[2][64][33];
    __shared__ unsigned long long sup_lds[32];
    __shared__ unsigned long long vb[32];
    __shared__ unsigned long long kbw[32];
    __shared__ int s_stop;
    float* dout = out + n * (POST_NMS * 5);
    for (int t = tid; t < POST_NMS * 5; t += 256) dout[t] = 0.f;
    if (tid < 32) { sup_lds[tid] = 0ull; kbw[tid] = 0ull; }
    if (tid == 0) s_stop = 0;
    if (tid < 64) {
        for (int i0 = 0; i0 < 2048; i0 += 64) {
            int i = i0 + lane;
            unsigned long long k = (i < PRE_NMS) ? skeys[(size_t)n * PRE_NMS + i] : ~0ull;
            unsigned long long m = __ballot(k != ~0ull);
            if (lane == 0) vb[i0 >> 6] = m;
        }
    }
    int r = tid >> 2, w0 = (tid & 3) * 8;
    {
        const unsigned long long* src = mat + ((size_t)n * 2048 + r) * 32 + w0;
        ulonglong2 a = *(const ulonglong2*)(src);
        ulonglong2 b = *(const ulonglong2*)(src + 2);
        ulonglong2 c2 = *(const ulonglong2*)(src + 4);
        ulonglong2 d = *(const ulonglong2*)(src + 6);
        unsigned long long* dst = &rb[0][r][w0];
        dst[0] = a.x; dst[1] = a.y; dst[2] = b.x; dst[3] = b.y;
        dst[4] = c2.x; dst[5] = c2.y; dst[6] = d.x; dst[7] = d.y;
    }
    __syncthreads();
    int total_kept = 0;
    for (int c = 0; c < 32; c++) {
        if (s_stop) break;
        int cur = c & 1, nxt = cur ^ 1;
        ulonglong2 pa, pb, pc, pd;
        bool pf = (c + 1 < 32);
        if (pf) {
            const unsigned long long* src = mat + ((size_t)n * 2048 + (c + 1) * 64 + r) * 32 + w0;
            pa = *(const ulonglong2*)(src);
            pb = *(const ulonglong2*)(src + 2);
            pc = *(const ulonglong2*)(src + 4);
            pd = *(const ulonglong2*)(src + 6);
        }
        if (tid < 64) {
            unsigned long long M = rb[cur][lane][c];
            unsigned long long supw = sup_lds[c];
            unsigned long long vbw = vb[c];
            unsigned long long km = 0ull;
#pragma unroll
            for (int ii = 0; ii < 64; ii++) {
                unsigned long long bit = 1ull << ii;
                if ((vbw & bit) && !(supw & bit)) {
                    km |= bit;
                    supw |= rl64(M, ii);
                }
            }
            if (lane == 0) {
                kbw[c] = km;
                total_kept += __popcll(km);
                if (total_kept >= POST_NMS) s_stop = 1;
            }
        }
        __syncthreads();
        {
            int w = tid & 31, g = tid >> 5;
            unsigned long long km2 = kbw[c];
            unsigned long long sub = (km2 >> (g * 8)) & 0xFFull;
            unsigned long long acc = 0ull;
            while (sub) {
                int bpos = __ffsll((long long)sub) - 1;
                sub &= sub - 1;
                acc |= rb[cur][g * 8 + bpos][w];
            }
            if (acc) atomicOr(&sup_lds[w], acc);
        }
        if (pf) {
            unsigned long long* dst = &rb[nxt][r][w0];
            dst[0] = pa.x; dst[1] = pa.y; dst[2] = pb.x; dst[3] = pb.y;
            dst[4] = pc.x; dst[5] = pc.y; dst[6] = pd.x; dst[7] = pd.y;
        }
        __syncthreads();
    }
    if (tid < 64) {
        int running = 0;
        for (int i0 = 0; i0 < 2048; i0 += 64) {
            int i = i0 + lane;
            bool kp = (i < PRE_NMS) && ((kbw[i >> 6] >> (i & 63)) & 1ull);
            unsigned long long m = __ballot(kp);
            if (kp) {
                int rk = running + __popcll(m & ((1ull << lane) - 1ull));
                if (rk < POST_NMS) {
                    const double* bp2 = bsort + ((size_t)n * 2048 + i) * 4;
                    unsigned long long k = skeys[(size_t)n * PRE_NMS + i];
                    double s = __longlong_as_double((long long)~k);
                    float* o = dout + rk * 5;
                    o[0] = (float)bp2[0]; o[1] = (float)bp2[1];
                    o[2] = (float)bp2[2]; o[3] = (float)bp2[3];
                    o[4] = (float)s;
                }
            }
            running += __popcll(m);
        }
    }
}

extern "C" void kernel_launch(void* const* d_in, const int* in_sizes, int n_in,
                              void* d_out, int out_size, void* d_ws, size_t ws_size,
                              hipStream_t stream) {
    (void)in_sizes; (void)n_in; (void)out_size; (void)ws_size;
    const float* feat   = (const float*)d_in[0];
    const float* conv_w = (const float*)d_in[1];
    const float* conv_b = (const float*)d_in[2];
    const float* det_w  = (const float*)d_in[3];
    const float* det_b  = (const float*)d_in[4];
    const float* reg_w  = (const float*)d_in[5];
    const float* reg_b  = (const float*)d_in[6];
    float* out = (float*)d_out;

    char* w = (char*)d_ws;
    double* E64 = (double*)w;                          w += (size_t)2304 * 16 * 8;
    double* EB64 = (double*)w;                         w += 128;
    double* PART = (double*)w;                         w += (size_t)4 << 23;                    // 33.6 MB
    unsigned long long* KEY64 = (unsigned long long*)w; w += (size_t)N_IMG * NPROP * 8;
    uint32_t* HISTS = (uint32_t*)w;                    w += (size_t)N_IMG * 4 * 2048 * 4;      // 128 KB
    uint32_t* CNT = (uint32_t*)w;                      w += 64;
    unsigned long long* CANDK = (unsigned long long*)w; w += (size_t)N_IMG * 2048 * 8;
    uint32_t* CANDI = (uint32_t*)w;                    w += (size_t)N_IMG * 2048 * 4;
    unsigned long long* SKEY = (unsigned long long*)w; w += (size_t)N_IMG * PRE_NMS * 8;
    double* BSORT = (double*)w;                        w += (size_t)N_IMG * 2048 * 4 * 8;
    double* AREA = (double*)w;                         w += (size_t)N_IMG * 2048 * 8;
    unsigned long long* MAT = (unsigned long long*)w;  w += (size_t)N_IMG * 2048 * 32 * 8;

    k_effw64<<<dim3(145), dim3(256), 0, stream>>>(conv_w, conv_b, det_w, det_b, reg_w, reg_b,
                                                  E64, EB64, HISTS, CNT);
    k_conv64<<<dim3(1024), dim3(256), 0, stream>>>(feat, E64, PART);
    k_findecode<<<dim3(256), dim3(256), 0, stream>>>(PART, EB64, KEY64, HISTS);
    for (int L = 1; L < 4; L++) {
        k_hist<<<dim3(64), dim3(256), 0, stream>>>(KEY64, HISTS, L);
    }
    k_collect<<<dim3(64), dim3(256), 0, stream>>>(KEY64, HISTS, CNT, CANDK, CANDI);
    k_finalsel<<<dim3(N_IMG), dim3(1024), 0, stream>>>(CNT, CANDK, CANDI, PART, EB64, SKEY, BSORT, AREA);
    k_iou2<<<dim3(N_IMG * 64), dim3(256), 0, stream>>>(BSORT, AREA, MAT);
    k_nms3<<<dim3(N_IMG), dim3(256), 0, stream>>>(SKEY, BSORT, MAT, out);
}

// Round 19
// 374.532 us; speedup vs baseline: 1.1435x; 1.0966x over previous
//
#include <hip/hip_runtime.h>
#include <hip/hip_bf16.h>
#include <hip/hip_fp16.h>
#include <stdint.h>
#include <math.h>

#define N_IMG 4
#define CIN 256
#define HFD 128
#define WFD 128
#define HW (HFD*WFD)        // 16384
#define NA 3
#define NPROP (NA*HW)       // 49152
#define PRE_NMS 2000
#define POST_NMS 300

__device__ __forceinline__ unsigned long long rl64(unsigned long long v, int i) {
    unsigned int lo = (unsigned int)__builtin_amdgcn_readlane((int)(unsigned int)v, i);
    unsigned int hi = (unsigned int)__builtin_amdgcn_readlane((int)(unsigned int)(v >> 32), i);
    return ((unsigned long long)hi << 32) | (unsigned long long)lo;
}

// PART layout: [chunk][c][p], chunk stride 1<<20 doubles, c stride 65536, p = (n<<14)+pos
__device__ __forceinline__ double sum4(const double* __restrict__ PART, size_t cp) {
    const size_t S = (size_t)1 << 20;
    return (PART[cp] + PART[cp + S]) + (PART[cp + 2 * S] + PART[cp + 3 * S]);
}

__device__ __forceinline__ void decode_box(int i, double dx, double dy, double dwv, double dhv,
                                           double& c1o, double& c2o, double& c3o, double& c4o) {
    int loc = i / 3, aa = i % 3;
    int hh = loc >> 7, wwi = loc & 127;
    double sx = (double)(wwi * 8), sy = (double)(hh * 8);
    double bx1 = (aa == 0) ? -91.0 : (aa == 1 ? -64.0 : -45.0);
    double by1 = (aa == 0) ? -45.0 : (aa == 1 ? -64.0 : -91.0);
    double x1 = sx + bx1, y1 = sy + by1, x2 = sx - bx1, y2 = sy - by1;
    double aw = x2 - x1, ahh = y2 - y1;
    double acx = y1 + aw * 0.5;   // (sic) swap, faithful to reference
    double acy = x1 + ahh * 0.5;  // (sic)
    double px = acx + dx * aw, py = acy + dy * ahh;
    double pw = aw * exp(dwv), ph = ahh * exp(dhv);
    double c1 = px - pw * 0.5, c2 = py - ph * 0.5, c3 = px + pw * 0.5, c4 = py + ph * 0.5;
    c1o = fmin(fmax(c1, 0.0), 1024.0);
    c2o = fmin(fmax(c2, 0.0), 1024.0);
    c3o = fmin(fmax(c3, 0.0), 1024.0);
    c4o = fmin(fmax(c4, 0.0), 1024.0);
}

// ---------------- K0: effective fp64 weights + selection-state init ----------------
__global__ __launch_bounds__(256) void k_effw64(const float* __restrict__ cw, const float* __restrict__ cb,
                                                const float* __restrict__ dw_, const float* __restrict__ db_,
                                                const float* __restrict__ rw_, const float* __restrict__ rb_,
                                                double* __restrict__ E64, double* __restrict__ EB64,
                                                unsigned long long* __restrict__ PSPREF,
                                                int* __restrict__ PSNEED,
                                                uint32_t* __restrict__ HIST,
                                                uint32_t* __restrict__ CNT)
{
    int b = blockIdx.x;
    int tid = threadIdx.x;
    if (b < 144) {
        __shared__ float hwl[15][260];
        __shared__ float wt[256][16];
        int k0 = b * 16;
        for (int idx = tid; idx < 15 * 256; idx += 256) {
            int c = idx >> 8, co = idx & 255;
            hwl[c][co] = (c < 3) ? dw_[c * 256 + co] : rw_[(c - 3) * 256 + co];
        }
        for (int idx = tid; idx < 4096; idx += 256) {
            int co = idx >> 4, kk = idx & 15;
            wt[co][kk] = cw[co * 2304 + k0 + kk];
        }
        __syncthreads();
        int kk = tid >> 4, c = tid & 15;
        double s = 0.0;
        if (c < 15) {
#pragma unroll 4
            for (int co = 0; co < 256; co++) s += (double)hwl[c][co] * (double)wt[co][kk];
        }
        E64[(k0 + kk) * 16 + c] = s;
    } else {
        if (tid < 16) {
            int c = tid;
            double s = 0.0; double hb = 0.0;
            if (c < 15) {
                const float* hw = (c < 3) ? (dw_ + c * 256) : (rw_ + (c - 3) * 256);
                for (int co = 0; co < 256; co++) s += (double)hw[co] * (double)cb[co];
                hb = (double)((c < 3) ? db_[c] : rb_[c - 3]);
            }
            EB64[c] = s + hb;
        }
        for (int i = tid; i < N_IMG * 2048; i += 256) HIST[i] = 0u;
        if (tid < N_IMG) { PSPREF[tid] = 0ull; PSNEED[tid] = PRE_NMS; CNT[tid] = 0u; }
    }
}

// ---------------- K1: dense fused 15-output 3x3 conv, fp64 acc, 4-way ci-split, 2-row tiles ----------------
// grid 1024 = 4 img x 64 row-pairs x 4 chunks(64 ci); block 256
// Weights: wave-uniform s_load from global E64 (readfirstlane-forced), no LDS staging.
__global__ __launch_bounds__(256, 4) void k_conv64(const float* __restrict__ feat,
                                                   const double* __restrict__ E64,
                                                   double* __restrict__ PART)
{
    __shared__ float in_t[8][4][136];   // [ci][row h0-1..h0+2][4 + col]
    int b = blockIdx.x;
    int chunk = b & 3; int hp = (b >> 2) & 63; int n = b >> 8;
    int h0 = hp * 2;
    int tid = threadIdx.x;
    int q = tid & 63;
    int row = q >> 5, qq = q & 31, w0 = qq * 4;
    int g = tid >> 6;
    double acc[4][4];
#pragma unroll
    for (int cc = 0; cc < 4; cc++)
#pragma unroll
        for (int px = 0; px < 4; px++) acc[cc][px] = 0.0;

    for (int sl = 0; sl < 8; sl++) {
        int ci0 = (chunk << 6) + sl * 8;
        for (int t = tid; t < 1024; t += 256) {
            int seg = t & 31;
            int rid = t >> 5;
            int ci = rid >> 2, dr = rid & 3;
            int gh = h0 - 1 + dr;
            float4 v = make_float4(0.f, 0.f, 0.f, 0.f);
            if (gh >= 0 && gh < HFD)
                v = *(const float4*)&feat[(((size_t)((n << 8) + ci0 + ci)) << 14) + (gh << 7) + (seg << 2)];
            *(float4*)&in_t[ci][dr][4 + (seg << 2)] = v;
        }
        __syncthreads();
        for (int ci = 0; ci < 8; ci++) {
            int kbase = ((ci0 + ci) * 9) << 4;
#pragma unroll
            for (int r = 0; r < 3; r++) {
                float4 f4 = *(const float4*)&in_t[ci][row + r][4 + w0];   // aligned, conflict-free
                float left   = __shfl_up(f4.w, 1);
                float right1 = __shfl_down(f4.x, 1);
                if (qq == 0)  left   = 0.f;   // col -1: conv zero-pad
                if (qq == 31) right1 = 0.f;   // col 128: conv zero-pad
                double fv[6];
                fv[0] = (double)left;
                fv[1] = (double)f4.x; fv[2] = (double)f4.y;
                fv[3] = (double)f4.z; fv[4] = (double)f4.w;
                fv[5] = (double)right1;
#pragma unroll
                for (int s = 0; s < 3; s++) {
                    int widx = __builtin_amdgcn_readfirstlane(kbase + (((r * 3 + s) << 4) + (g << 2)));
                    const double* wp = E64 + widx;
                    double2 wv0 = *(const double2*)(wp);
                    double2 wv1 = *(const double2*)(wp + 2);
#pragma unroll
                    for (int px = 0; px < 4; px++) {
                        double f = fv[s + px];
                        acc[0][px] += wv0.x * f;
                        acc[1][px] += wv0.y * f;
                        acc[2][px] += wv1.x * f;
                        acc[3][px] += wv1.y * f;
                    }
                }
            }
        }
        __syncthreads();
    }
    int gpos = (n << 14) + ((h0 + row) << 7) + w0;
    double* base = PART + ((size_t)chunk << 20) + gpos;
#pragma unroll
    for (int cc = 0; cc < 4; cc++) {
        int c = g * 4 + cc;
        if (c < 15) {
            double2 s0; s0.x = acc[cc][0]; s0.y = acc[cc][1];
            double2 s1; s1.x = acc[cc][2]; s1.y = acc[cc][3];
            *(double2*)(base + (size_t)c * 65536) = s0;
            *(double2*)(base + (size_t)c * 65536 + 2) = s1;
        }
    }
}

// ---------------- K2: combine + fp64 decode -> KEY64, fused radix L0 histogram ----------------
__global__ __launch_bounds__(256) void k_findecode(const double* __restrict__ PART,
                                                   const double* __restrict__ EB64,
                                                   unsigned long long* __restrict__ KEY64,
                                                   uint32_t* __restrict__ HIST)
{
    __shared__ uint32_t h2[2048];
    int tid = threadIdx.x;
    for (int i = tid; i < 2048; i += 256) h2[i] = 0u;
    __syncthreads();
    int p = blockIdx.x * 256 + tid;   // 65536; block spans one image
    int n = p >> 14, pos = p & 16383;
    double L[15];
#pragma unroll
    for (int c = 0; c < 15; c++)
        L[c] = sum4(PART, (size_t)c * 65536 + p) + EB64[c];
#pragma unroll
    for (int a = 0; a < 3; a++) {
        double logit = L[a];
        double score = 1.0 / (1.0 + exp(-logit));
        int i = a * HW + pos;
        double c1, c2, c3, c4;
        decode_box(i, L[3 + a], L[6 + a], L[9 + a], L[12 + a], c1, c2, c3, c4);
        bool valid = (score > 0.3) && (c3 - c1 > 0.0) && (c4 - c2 > 0.0);
        unsigned long long key = valid ? ~((unsigned long long)__double_as_longlong(score)) : ~0ull;
        KEY64[(size_t)n * NPROP + i] = key;
        atomicAdd(&h2[(uint32_t)(key >> 53)], 1u);
    }
    __syncthreads();
    uint32_t* G = HIST + n * 2048;
    for (int i = tid; i < 2048; i += 256) {
        uint32_t v = h2[i];
        if (v) atomicAdd(&G[i], v);
    }
}

// ---------------- selection: grid-parallel radix passes with global state ----------------
__global__ __launch_bounds__(256) void k_hist(const unsigned long long* __restrict__ KEY64,
                                              const unsigned long long* __restrict__ PSPREF,
                                              uint32_t* __restrict__ HIST, int L)
{
    __shared__ uint32_t h[2048];
    int blk = blockIdx.x; int n = blk >> 4, sub = blk & 15;
    int tid = threadIdx.x;
    for (int i = tid; i < 2048; i += 256) h[i] = 0u;
    __syncthreads();
    int sh = 53 - 11 * L;
    unsigned long long pref = PSPREF[n];
    const unsigned long long* K = KEY64 + (size_t)n * NPROP + sub * 3072;
    for (int i = tid; i < 3072; i += 256) {
        unsigned long long k = K[i];
        if ((k >> (sh + 11)) == pref) atomicAdd(&h[(uint32_t)((k >> sh) & 2047ull)], 1u);
    }
    __syncthreads();
    uint32_t* G = HIST + n * 2048;
    for (int i = tid; i < 2048; i += 256) {
        uint32_t v = h[i];
        if (v) atomicAdd(&G[i], v);
    }
}

__global__ __launch_bounds__(256) void k_pick(uint32_t* __restrict__ HIST,
                                              unsigned long long* __restrict__ PSPREF,
                                              int* __restrict__ PSNEED)
{
    int n = blockIdx.x; int tid = threadIdx.x;
    __shared__ uint32_t hl[2048];
    __shared__ uint32_t psum[256];
    uint32_t* G = HIST + n * 2048;
    for (int i = tid; i < 2048; i += 256) hl[i] = G[i];
    __syncthreads();
    {
        uint32_t s = 0;
        for (int qq = 0; qq < 8; qq++) s += hl[tid * 8 + qq];
        psum[tid] = s;
    }
    __syncthreads();
    if (tid == 0) {
        int need = PSNEED[n];
        unsigned long long pref = PSPREF[n];
        uint32_t cum = 0; int g = 255;
        for (int t = 0; t < 256; t++) { uint32_t c = psum[t]; if (cum + c >= (uint32_t)need) { g = t; break; } cum += c; }
        int bsel = g * 8 + 7;
        for (int t = g * 8; t < g * 8 + 8; t++) { uint32_t c = hl[t]; if (cum + c >= (uint32_t)need) { bsel = t; break; } cum += c; }
        PSNEED[n] = need - (int)cum;
        PSPREF[n] = (pref << 11) | (unsigned long long)bsel;
    }
    __syncthreads();
    for (int i = tid; i < 2048; i += 256) G[i] = 0u;
}

__global__ __launch_bounds__(256) void k_collect(const unsigned long long* __restrict__ KEY64,
                                                 const unsigned long long* __restrict__ PSPREF,
                                                 uint32_t* __restrict__ CNT,
                                                 unsigned long long* __restrict__ CANDK,
                                                 uint32_t* __restrict__ CANDI)
{
    int blk = blockIdx.x; int n = blk >> 4, sub = blk & 15;
    int tid = threadIdx.x;
    unsigned long long pref44 = PSPREF[n];
    const unsigned long long* K = KEY64 + (size_t)n * NPROP;
    int base = sub * 3072;
    for (int i = tid; i < 3072; i += 256) {
        unsigned long long k = K[base + i];
        if (k != ~0ull && (k >> 20) <= pref44) {
            uint32_t p2 = atomicAdd(&CNT[n], 1u);
            if (p2 < 2048u) { CANDK[n * 2048 + p2] = k; CANDI[n * 2048 + p2] = (uint32_t)(base + i); }
        }
    }
}

__global__ __launch_bounds__(1024) void k_finalsel(const uint32_t* __restrict__ CNT,
                                                   const unsigned long long* __restrict__ CANDK,
                                                   const uint32_t* __restrict__ CANDI,
                                                   const double* __restrict__ PART,
                                                   const double* __restrict__ EB64,
                                                   unsigned long long* __restrict__ skeys,
                                                   double* __restrict__ bsort,
                                                   double* __restrict__ area)
{
    int n = blockIdx.x; int tid = threadIdx.x;
    __shared__ unsigned long long selk[2048];
    __shared__ uint32_t seli[2048];
    uint32_t cnt = CNT[n]; if (cnt > 2048u) cnt = 2048u;
    for (int t = tid; t < 2048; t += 1024) {
        if (t < (int)cnt) { selk[t] = CANDK[n * 2048 + t]; seli[t] = CANDI[n * 2048 + t]; }
        else { selk[t] = ~0ull; seli[t] = 0xFFFFFFFFu; }
    }
    __syncthreads();
    for (unsigned k2 = 2; k2 <= 2048; k2 <<= 1) {
        for (unsigned jx = k2 >> 1; jx > 0; jx >>= 1) {
            for (int t = tid; t < 2048; t += 1024) {
                unsigned ixj = (unsigned)t ^ jx;
                if (ixj > (unsigned)t) {
                    bool up = ((t & k2) == 0);
                    unsigned long long ka = selk[t], kb = selk[ixj];
                    uint32_t ia = seli[t], ib = seli[ixj];
                    bool agt = (ka > kb) || (ka == kb && ia > ib);
                    if (up ? agt : !agt) {
                        selk[t] = kb; selk[ixj] = ka;
                        seli[t] = ib; seli[ixj] = ia;
                    }
                }
            }
            __syncthreads();
        }
    }
    for (int t = tid; t < 2048; t += 1024) {
        bool valid = (t < PRE_NMS) && (selk[t] != ~0ull);
        if (t < PRE_NMS) skeys[(size_t)n * PRE_NMS + t] = valid ? selk[t] : ~0ull;
        double b0 = 0, b1 = 0, b2 = 0, b3 = 0;
        if (valid) {
            int i = (int)seli[t];
            int a = i >> 14, pos = i & 16383;
            size_t p = ((size_t)n << 14) + pos;
            double dx  = sum4(PART, (size_t)(3 + a)  * 65536 + p) + EB64[3 + a];
            double dy  = sum4(PART, (size_t)(6 + a)  * 65536 + p) + EB64[6 + a];
            double dwv = sum4(PART, (size_t)(9 + a)  * 65536 + p) + EB64[9 + a];
            double dhv = sum4(PART, (size_t)(12 + a) * 65536 + p) + EB64[12 + a];
            decode_box(i, dx, dy, dwv, dhv, b0, b1, b2, b3);
        }
        double* bs = bsort + (((size_t)(n * 2048 + t)) << 2);
        bs[0] = b0; bs[1] = b1; bs[2] = b2; bs[3] = b3;
        area[(size_t)n * 2048 + t] = fmax(b2 - b0, 0.0) * fmax(b3 - b1, 0.0);
    }
}

// ---------------- K4: pairwise IoU > 0.7 bitmask (32-row tiles, upper-triangle chunks only) ----------------
__global__ __launch_bounds__(256) void k_iou2(const double* __restrict__ bsort,
                                              const double* __restrict__ area,
                                              unsigned long long* __restrict__ mat)
{
    int blk = blockIdx.x; int n = blk >> 6; int rt = blk & 63;
    int tid = threadIdx.x;
    int r = tid >> 3, g = tid & 7;
    int i = rt * 32 + r;
    const double* bp = bsort + ((size_t)n * 2048 + i) * 4;
    double bx0 = bp[0], bx1_ = bp[1], bx2_ = bp[2], bx3 = bp[3];
    double ai = area[(size_t)n * 2048 + i];
    __shared__ double cbx[512][4];
    __shared__ double ca[512];
    for (int cc = 0; cc < 4; cc++) {
        if ((cc + 1) * 512 <= rt * 32) continue;
        __syncthreads();
        for (int idx = tid; idx < 512; idx += 256) {
            const double* sp = bsort + ((size_t)n * 2048 + cc * 512 + idx) * 4;
            cbx[idx][0] = sp[0]; cbx[idx][1] = sp[1]; cbx[idx][2] = sp[2]; cbx[idx][3] = sp[3];
            ca[idx] = area[(size_t)n * 2048 + cc * 512 + idx];
        }
        __syncthreads();
        unsigned long long wd = 0ull;
        for (int jb = 0; jb < 64; jb++) {
            int jr = (jb + g * 9) & 63;
            int jj = g * 64 + jr;
            double ix1 = fmax(bx0, cbx[jj][0]);
            double iy1 = fmax(bx1_, cbx[jj][1]);
            double ix2 = fmin(bx2_, cbx[jj][2]);
            double iy2 = fmin(bx3, cbx[jj][3]);
            double inter = fmax(ix2 - ix1, 0.0) * fmax(iy2 - iy1, 0.0);
            double den = fmax(ai + ca[jj] - inter, 1e-9);
            double iou = inter / den;
            if (iou > 0.7) wd |= (1ull << jr);
        }
        mat[((size_t)n * 2048 + i) * 32 + cc * 8 + g] = wd;
    }
}

// ---------------- K5: chunked NMS — early exit at 300 kept + parallel cross-chunk OR ----------------
__global__ __launch_bounds__(256) void k_nms3(const unsigned long long* __restrict__ skeys,
                                              const double* __restrict__ bsort,
                                              const unsigned long long* __restrict__ mat,
                                              float* __restrict__ out)
{
    int n = blockIdx.x; int tid = threadIdx.x;
    int lane = tid & 63;
    __shared__ unsigned long long rb[2][64][33];
    __shared__ unsigned long long sup_lds[32];
    __shared__ unsigned long long vb[32];
    __shared__ unsigned long long kbw[32];
    __shared__ int s_stop;
    float* dout = out + n * (POST_NMS * 5);
    for (int t = tid; t < POST_NMS * 5; t += 256) dout[t] = 0.f;
    if (tid < 32) { sup_lds[tid] = 0ull; kbw[tid] = 0ull; }
    if (tid == 0) s_stop = 0;
    if (tid < 64) {
        for (int i0 = 0; i0 < 2048; i0 += 64) {
            int i = i0 + lane;
            unsigned long long k = (i < PRE_NMS) ? skeys[(size_t)n * PRE_NMS + i] : ~0ull;
            unsigned long long m = __ballot(k != ~0ull);
            if (lane == 0) vb[i0 >> 6] = m;
        }
    }
    int r = tid >> 2, w0 = (tid & 3) * 8;
    {
        const unsigned long long* src = mat + ((size_t)n * 2048 + r) * 32 + w0;
        ulonglong2 a = *(const ulonglong2*)(src);
        ulonglong2 b = *(const ulonglong2*)(src + 2);
        ulonglong2 c2 = *(const ulonglong2*)(src + 4);
        ulonglong2 d = *(const ulonglong2*)(src + 6);
        unsigned long long* dst = &rb[0][r][w0];
        dst[0] = a.x; dst[1] = a.y; dst[2] = b.x; dst[3] = b.y;
        dst[4] = c2.x; dst[5] = c2.y; dst[6] = d.x; dst[7] = d.y;
    }
    __syncthreads();
    int total_kept = 0;
    for (int c = 0; c < 32; c++) {
        if (s_stop) break;
        int cur = c & 1, nxt = cur ^ 1;
        ulonglong2 pa, pb, pc, pd;
        bool pf = (c + 1 < 32);
        if (pf) {
            const unsigned long long* src = mat + ((size_t)n * 2048 + (c + 1) * 64 + r) * 32 + w0;
            pa = *(const ulonglong2*)(src);
            pb = *(const ulonglong2*)(src + 2);
            pc = *(const ulonglong2*)(src + 4);
            pd = *(const ulonglong2*)(src + 6);
        }
        if (tid < 64) {
            unsigned long long M = rb[cur][lane][c];
            unsigned long long supw = sup_lds[c];
            unsigned long long vbw = vb[c];
            unsigned long long km = 0ull;
#pragma unroll
            for (int ii = 0; ii < 64; ii++) {
                unsigned long long bit = 1ull << ii;
                if ((vbw & bit) && !(supw & bit)) {
                    km |= bit;
                    supw |= rl64(M, ii);
                }
            }
            if (lane == 0) {
                kbw[c] = km;
                total_kept += __popcll(km);
                if (total_kept >= POST_NMS) s_stop = 1;
            }
        }
        __syncthreads();
        {
            int w = tid & 31, g = tid >> 5;
            unsigned long long km2 = kbw[c];
            unsigned long long sub = (km2 >> (g * 8)) & 0xFFull;
            unsigned long long acc = 0ull;
            while (sub) {
                int bpos = __ffsll((long long)sub) - 1;
                sub &= sub - 1;
                acc |= rb[cur][g * 8 + bpos][w];
            }
            if (acc) atomicOr(&sup_lds[w], acc);
        }
        if (pf) {
            unsigned long long* dst = &rb[nxt][r][w0];
            dst[0] = pa.x; dst[1] = pa.y; dst[2] = pb.x; dst[3] = pb.y;
            dst[4] = pc.x; dst[5] = pc.y; dst[6] = pd.x; dst[7] = pd.y;
        }
        __syncthreads();
    }
    if (tid < 64) {
        int running = 0;
        for (int i0 = 0; i0 < 2048; i0 += 64) {
            int i = i0 + lane;
            bool kp = (i < PRE_NMS) && ((kbw[i >> 6] >> (i & 63)) & 1ull);
            unsigned long long m = __ballot(kp);
            if (kp) {
                int rk = running + __popcll(m & ((1ull << lane) - 1ull));
                if (rk < POST_NMS) {
                    const double* bp2 = bsort + ((size_t)n * 2048 + i) * 4;
                    unsigned long long k = skeys[(size_t)n * PRE_NMS + i];
                    double s = __longlong_as_double((long long)~k);
                    float* o = dout + rk * 5;
                    o[0] = (float)bp2[0]; o[1] = (float)bp2[1];
                    o[2] = (float)bp2[2]; o[3] = (float)bp2[3];
                    o[4] = (float)s;
                }
            }
            running += __popcll(m);
        }
    }
}

extern "C" void kernel_launch(void* const* d_in, const int* in_sizes, int n_in,
                              void* d_out, int out_size, void* d_ws, size_t ws_size,
                              hipStream_t stream) {
    (void)in_sizes; (void)n_in; (void)out_size; (void)ws_size;
    const float* feat   = (const float*)d_in[0];
    const float* conv_w = (const float*)d_in[1];
    const float* conv_b = (const float*)d_in[2];
    const float* det_w  = (const float*)d_in[3];
    const float* det_b  = (const float*)d_in[4];
    const float* reg_w  = (const float*)d_in[5];
    const float* reg_b  = (const float*)d_in[6];
    float* out = (float*)d_out;

    char* w = (char*)d_ws;
    double* E64 = (double*)w;                          w += (size_t)2304 * 16 * 8;
    double* EB64 = (double*)w;                         w += 128;
    double* PART = (double*)w;                         w += (size_t)4 << 23;                    // 33.6 MB
    unsigned long long* KEY64 = (unsigned long long*)w; w += (size_t)N_IMG * NPROP * 8;
    unsigned long long* PSPREF = (unsigned long long*)w; w += N_IMG * 8;
    int* PSNEED = (int*)w;                             w += 64;
    uint32_t* HIST = (uint32_t*)w;                     w += (size_t)N_IMG * 2048 * 4;
    uint32_t* CNT = (uint32_t*)w;                      w += 64;
    unsigned long long* CANDK = (unsigned long long*)w; w += (size_t)N_IMG * 2048 * 8;
    uint32_t* CANDI = (uint32_t*)w;                    w += (size_t)N_IMG * 2048 * 4;
    unsigned long long* SKEY = (unsigned long long*)w; w += (size_t)N_IMG * PRE_NMS * 8;
    double* BSORT = (double*)w;                        w += (size_t)N_IMG * 2048 * 4 * 8;
    double* AREA = (double*)w;                         w += (size_t)N_IMG * 2048 * 8;
    unsigned long long* MAT = (unsigned long long*)w;  w += (size_t)N_IMG * 2048 * 32 * 8;

    k_effw64<<<dim3(145), dim3(256), 0, stream>>>(conv_w, conv_b, det_w, det_b, reg_w, reg_b,
                                                  E64, EB64, PSPREF, PSNEED, HIST, CNT);
    k_conv64<<<dim3(1024), dim3(256), 0, stream>>>(feat, E64, PART);
    k_findecode<<<dim3(256), dim3(256), 0, stream>>>(PART, EB64, KEY64, HIST);
    k_pick<<<dim3(N_IMG), dim3(256), 0, stream>>>(HIST, PSPREF, PSNEED);     // L0
    for (int L = 1; L < 4; L++) {
        k_hist<<<dim3(64), dim3(256), 0, stream>>>(KEY64, PSPREF, HIST, L);
        k_pick<<<dim3(N_IMG), dim3(256), 0, stream>>>(HIST, PSPREF, PSNEED);
    }
    k_collect<<<dim3(64), dim3(256), 0, stream>>>(KEY64, PSPREF, CNT, CANDK, CANDI);
    k_finalsel<<<dim3(N_IMG), dim3(1024), 0, stream>>>(CNT, CANDK, CANDI, PART, EB64, SKEY, BSORT, AREA);
    k_iou2<<<dim3(N_IMG * 64), dim3(256), 0, stream>>>(BSORT, AREA, MAT);
    k_nms3<<<dim3(N_IMG), dim3(256), 0, stream>>>(SKEY, BSORT, MAT, out);
}